// Round 1
// baseline (2031.979 us; speedup 1.0000x reference)
//
#include <hip/hip_runtime.h>
#include <cstdint>
#include <cstddef>

#define NNODE 4096
#define FIND  2048
#define HD_   256
#define NC_   10
#define THRESH_ 0.05f

typedef unsigned long long u64;

// ---------------- row normalize ----------------
__global__ void rownorm_k(const float* __restrict__ x, float* __restrict__ xn){
  int row = blockIdx.x; int t = threadIdx.x;
  const float4* xr = reinterpret_cast<const float4*>(x + (size_t)row*FIND);
  float4* xo = reinterpret_cast<float4*>(xn + (size_t)row*FIND);
  float s = 0.f;
  #pragma unroll
  for (int i = 0; i < FIND/4/256; ++i){
    float4 v = xr[t + i*256];
    s += v.x*v.x + v.y*v.y + v.z*v.z + v.w*v.w;
  }
  #pragma unroll
  for (int o = 32; o > 0; o >>= 1) s += __shfl_down(s, o);
  __shared__ float red[4];
  __shared__ float invn;
  if ((t & 63) == 0) red[t >> 6] = s;
  __syncthreads();
  if (t == 0) invn = rsqrtf(red[0] + red[1] + red[2] + red[3]);
  __syncthreads();
  float inv = invn;
  #pragma unroll
  for (int i = 0; i < FIND/4/256; ++i){
    float4 v = xr[t + i*256];
    float4 w; w.x = v.x*inv; w.y = v.y*inv; w.z = v.z*inv; w.w = v.w*inv;
    xo[t + i*256] = w;
  }
}

// ---------------- weight prep ----------------
// R [K, H*F] row-major -> outT [F, K], summing over H head blocks.
__global__ void fold_transpose(const float* __restrict__ R, float* __restrict__ outT,
                               int K, int H, int F, int total){
  int idx = blockIdx.x*256 + threadIdx.x;
  if (idx >= total) return;
  int k = idx % K, f = idx / K;
  float s = 0.f;
  for (int h = 0; h < H; ++h) s += R[(size_t)k*(H*F) + (size_t)h*F + f];
  outT[(size_t)f*K + k] = s;
}

__global__ void bfold_k(const float* __restrict__ b, float* __restrict__ out, int H, int F){
  int f = threadIdx.x;
  if (f < F){
    float s = 0.f;
    for (int h = 0; h < H; ++h) s += b[h*F + f];
    out[f] = s;
  }
}

// ---------------- NT GEMM: C[M,Nc] = A[M,K] * B[Nc,K]^T ----------------
// EPI: 0 = store, 1 = +bias then leakyrelu(param), 2 = bitpack (val > param) into Mk
template<int EPI>
__launch_bounds__(256)
__global__ void gemm_nt(const float* __restrict__ A, const float* __restrict__ B,
                        float* __restrict__ C, u64* __restrict__ Mk,
                        int M, int Nc, int K, int lda, int ldb, int ldc,
                        const float* __restrict__ bias, float param){
  __shared__ float smem[2*32*68];
  float* sA = smem;
  float* sB = smem + 32*68;
  const int t  = threadIdx.x;
  const int tx = t & 15, ty = t >> 4;
  const int row0 = blockIdx.y * 64, col0 = blockIdx.x * 64;
  float acc[4][4] = {};
  for (int k0 = 0; k0 < K; k0 += 32){
    __syncthreads();
    #pragma unroll
    for (int it = 0; it < 2; ++it){
      int idx = t + it*256;            // 0..511
      int r = idx >> 3, c4 = idx & 7;  // r 0..63, c4 0..7
      float4 va = *reinterpret_cast<const float4*>(A + (size_t)(row0 + r)*lda + k0 + c4*4);
      float4 vb = *reinterpret_cast<const float4*>(B + (size_t)(col0 + r)*ldb + k0 + c4*4);
      int kb = c4*4;
      sA[(kb+0)*68 + r] = va.x; sA[(kb+1)*68 + r] = va.y;
      sA[(kb+2)*68 + r] = va.z; sA[(kb+3)*68 + r] = va.w;
      sB[(kb+0)*68 + r] = vb.x; sB[(kb+1)*68 + r] = vb.y;
      sB[(kb+2)*68 + r] = vb.z; sB[(kb+3)*68 + r] = vb.w;
    }
    __syncthreads();
    #pragma unroll
    for (int kk = 0; kk < 32; ++kk){
      float4 a = *reinterpret_cast<const float4*>(&sA[kk*68 + ty*4]);
      float4 b = *reinterpret_cast<const float4*>(&sB[kk*68 + tx*4]);
      acc[0][0] += a.x*b.x; acc[0][1] += a.x*b.y; acc[0][2] += a.x*b.z; acc[0][3] += a.x*b.w;
      acc[1][0] += a.y*b.x; acc[1][1] += a.y*b.y; acc[1][2] += a.y*b.z; acc[1][3] += a.y*b.w;
      acc[2][0] += a.z*b.x; acc[2][1] += a.z*b.y; acc[2][2] += a.z*b.z; acc[2][3] += a.z*b.w;
      acc[3][0] += a.w*b.x; acc[3][1] += a.w*b.y; acc[3][2] += a.w*b.z; acc[3][3] += a.w*b.w;
    }
  }
  if (EPI == 2){
    __syncthreads();
    float* Ct = smem;  // 64 x 68
    #pragma unroll
    for (int i = 0; i < 4; ++i)
      #pragma unroll
      for (int j = 0; j < 4; ++j)
        Ct[(ty*4 + i)*68 + tx*4 + j] = acc[i][j];
    __syncthreads();
    if (t < 64){
      int r = t;
      u64 bits = 0ull;
      #pragma unroll
      for (int c = 0; c < 64; ++c)
        bits |= (Ct[r*68 + c] > param) ? (1ull << c) : 0ull;
      Mk[(size_t)(row0 + r)*(Nc >> 6) + (col0 >> 6)] = bits;
    }
  } else {
    #pragma unroll
    for (int i = 0; i < 4; ++i){
      int row = row0 + ty*4 + i;
      float v0 = acc[i][0], v1 = acc[i][1], v2 = acc[i][2], v3 = acc[i][3];
      if (EPI == 1){
        int c = col0 + tx*4;
        v0 += bias[c+0]; v1 += bias[c+1]; v2 += bias[c+2]; v3 += bias[c+3];
        v0 = v0 > 0.f ? v0 : param*v0;
        v1 = v1 > 0.f ? v1 : param*v1;
        v2 = v2 > 0.f ? v2 : param*v2;
        v3 = v3 > 0.f ? v3 : param*v3;
      }
      float4 v; v.x = v0; v.y = v1; v.z = v2; v.w = v3;
      *reinterpret_cast<float4*>(C + (size_t)row*ldc + col0 + tx*4) = v;
    }
  }
}

// ---------------- el / er per node ----------------
template<int H>
__global__ void el_er_k(const float* __restrict__ feat, int ldf,
                        const float* __restrict__ al, const float* __restrict__ ar,
                        float* __restrict__ el, float* __restrict__ er){
  int n = blockIdx.x, t = threadIdx.x;
  __shared__ float red[8];
  #pragma unroll
  for (int h = 0; h < H; ++h){
    float v = feat[(size_t)n*ldf + h*HD_ + t];
    float a = v * al[h*HD_ + t];
    float b = v * ar[h*HD_ + t];
    #pragma unroll
    for (int o = 32; o > 0; o >>= 1){ a += __shfl_down(a, o); b += __shfl_down(b, o); }
    if ((t & 63) == 0){ red[t >> 6] = a; red[4 + (t >> 6)] = b; }
    __syncthreads();
    if (t == 0){
      el[n*H + h] = red[0] + red[1] + red[2] + red[3];
      er[n*H + h] = red[4] + red[5] + red[6] + red[7];
    }
    __syncthreads();
  }
}

// ---------------- softmax stats (max, denom) per dst ----------------
template<int H>
__global__ void stats_k(const u64* __restrict__ Mk,
                        const float* __restrict__ el, const float* __restrict__ er,
                        float* __restrict__ mo, float* __restrict__ lo){
  int d = blockIdx.x, t = threadIdx.x;
  float erd[H], mx[H];
  #pragma unroll
  for (int h = 0; h < H; ++h){ erd[h] = er[d*H + h]; mx[h] = -1e30f; }
  for (int s = t; s < NNODE; s += 256){
    u64 w = Mk[(size_t)d*64 + (s >> 6)];
    if ((w >> (s & 63)) & 1ull){
      #pragma unroll
      for (int h = 0; h < H; ++h){
        float e = erd[h] + el[s*H + h];
        e = e > 0.f ? e : 0.2f*e;
        mx[h] = fmaxf(mx[h], e);
      }
    }
  }
  __shared__ float red[H*4];
  __shared__ float mfin[H];
  #pragma unroll
  for (int h = 0; h < H; ++h){
    float v = mx[h];
    #pragma unroll
    for (int o = 32; o > 0; o >>= 1) v = fmaxf(v, __shfl_down(v, o));
    if ((t & 63) == 0) red[h*4 + (t >> 6)] = v;
  }
  __syncthreads();
  if (t == 0){
    #pragma unroll
    for (int h = 0; h < H; ++h)
      mfin[h] = fmaxf(fmaxf(red[h*4+0], red[h*4+1]), fmaxf(red[h*4+2], red[h*4+3]));
  }
  __syncthreads();
  float sm[H];
  #pragma unroll
  for (int h = 0; h < H; ++h) sm[h] = 0.f;
  for (int s = t; s < NNODE; s += 256){
    u64 w = Mk[(size_t)d*64 + (s >> 6)];
    if ((w >> (s & 63)) & 1ull){
      #pragma unroll
      for (int h = 0; h < H; ++h){
        float e = erd[h] + el[s*H + h];
        e = e > 0.f ? e : 0.2f*e;
        sm[h] += __expf(e - mfin[h]);
      }
    }
  }
  __syncthreads();
  #pragma unroll
  for (int h = 0; h < H; ++h){
    float v = sm[h];
    #pragma unroll
    for (int o = 32; o > 0; o >>= 1) v += __shfl_down(v, o);
    if ((t & 63) == 0) red[h*4 + (t >> 6)] = v;
  }
  __syncthreads();
  if (t == 0){
    #pragma unroll
    for (int h = 0; h < H; ++h){
      mo[d*H + h] = mfin[h];
      lo[d*H + h] = red[h*4+0] + red[h*4+1] + red[h*4+2] + red[h*4+3];
    }
  }
}

// ---------------- aggregation: out[d,f] = sum_h sum_s alpha*feat + res + bias ----------------
template<int H, bool RELU>
__global__ void agg_k(const float* __restrict__ feat, int ldf,
                      const u64* __restrict__ Mk,
                      const float* __restrict__ el, const float* __restrict__ er,
                      const float* __restrict__ mo, const float* __restrict__ lo,
                      const float* __restrict__ res, int ldres,
                      const float* __restrict__ bias,
                      float* __restrict__ out){
  int d = blockIdx.x, t = threadIdx.x;
  float erd[H], md[H], li[H], acc[H];
  #pragma unroll
  for (int h = 0; h < H; ++h){
    erd[h] = er[d*H + h];
    md[h]  = mo[d*H + h];
    li[h]  = 1.f / lo[d*H + h];
    acc[h] = 0.f;
  }
  for (int w = 0; w < 64; ++w){
    u64 bits = Mk[(size_t)d*64 + w];
    while (bits){
      int b = __builtin_ctzll(bits);
      bits &= bits - 1ull;
      int s = w*64 + b;
      #pragma unroll
      for (int h = 0; h < H; ++h){
        float e = erd[h] + el[s*H + h];
        e = e > 0.f ? e : 0.2f*e;
        float wt = __expf(e - md[h]) * li[h];
        acc[h] += wt * feat[(size_t)s*ldf + h*HD_ + t];
      }
    }
  }
  float v = 0.f;
  #pragma unroll
  for (int h = 0; h < H; ++h) v += acc[h];
  v += res[(size_t)d*ldres + t];
  v += bias[t];
  if (RELU) v = fmaxf(v, 0.f);
  out[(size_t)d*HD_ + t] = v;
}

// ---------------- concat z = [x, h3] ----------------
__global__ void concat_k(const float* __restrict__ x, const float* __restrict__ h3,
                         float* __restrict__ z){
  int idx = blockIdx.x*256 + threadIdx.x;
  if (idx >= NNODE*2304) return;
  int row = idx / 2304, c = idx % 2304;
  z[idx] = (c < FIND) ? x[(size_t)row*FIND + c] : h3[(size_t)row*HD_ + (c - FIND)];
}

// ---------------- classifier head: out[row, 0..9] = A[row,:] @ W + b ----------------
__global__ void head_k(const float* __restrict__ A, int K, const float* __restrict__ W,
                       const float* __restrict__ b, float* __restrict__ out){
  int row = blockIdx.x, t = threadIdx.x;
  float p[NC_];
  #pragma unroll
  for (int j = 0; j < NC_; ++j) p[j] = 0.f;
  for (int k = t; k < K; k += 256){
    float a = A[(size_t)row*K + k];
    #pragma unroll
    for (int j = 0; j < NC_; ++j) p[j] += a * W[k*NC_ + j];
  }
  #pragma unroll
  for (int j = 0; j < NC_; ++j){
    #pragma unroll
    for (int o = 32; o > 0; o >>= 1) p[j] += __shfl_down(p[j], o);
  }
  __shared__ float red[4][NC_];
  if ((t & 63) == 0){
    #pragma unroll
    for (int j = 0; j < NC_; ++j) red[t >> 6][j] = p[j];
  }
  __syncthreads();
  if (t < NC_)
    out[(size_t)row*NC_ + t] = red[0][t] + red[1][t] + red[2][t] + red[3][t] + b[t];
}

// ---------------- launch ----------------
extern "C" void kernel_launch(void* const* d_in, const int* in_sizes, int n_in,
                              void* d_out, int out_size, void* d_ws, size_t ws_size,
                              hipStream_t stream){
  const float* x   = (const float*)d_in[0];
  const float* W0  = (const float*)d_in[1];
  const float* al0 = (const float*)d_in[2];
  const float* ar0 = (const float*)d_in[3];
  const float* b0  = (const float*)d_in[4];
  const float* R0  = (const float*)d_in[5];
  const float* W1  = (const float*)d_in[6];
  const float* al1 = (const float*)d_in[7];
  const float* ar1 = (const float*)d_in[8];
  const float* b1  = (const float*)d_in[9];
  const float* R1  = (const float*)d_in[10];
  const float* W2  = (const float*)d_in[11];
  const float* al2 = (const float*)d_in[12];
  const float* ar2 = (const float*)d_in[13];
  const float* b2  = (const float*)d_in[14];
  const float* Wl1 = (const float*)d_in[15];
  const float* bl1 = (const float*)d_in[16];
  const float* Wc1 = (const float*)d_in[17];
  const float* bc1 = (const float*)d_in[18];
  const float* Wc2 = (const float*)d_in[19];
  const float* bc2 = (const float*)d_in[20];
  (void)in_sizes; (void)n_in; (void)out_size; (void)ws_size;

  char* ws = (char*)d_ws;
  size_t off = 0;
  auto alloc = [&](size_t bytes)->char*{
    char* p = ws + off; off += (bytes + 255) & ~(size_t)255; return p;
  };
  u64*   MASK  = (u64*)  alloc((size_t)NNODE*64*8);
  float* W0R0T = (float*)alloc((size_t)1280*2048*4);
  float* W1R1T = (float*)alloc((size_t)1280*256*4);
  float* W2T   = (float*)alloc((size_t)256*256*4);
  float* WL1T  = (float*)alloc((size_t)1024*2304*4);
  float* BF0   = (float*)alloc(256*4);
  float* BF1   = (float*)alloc(256*4);
  float* EL    = (float*)alloc((size_t)NNODE*4*4);
  float* ER    = (float*)alloc((size_t)NNODE*4*4);
  float* MO    = (float*)alloc((size_t)NNODE*4*4);
  float* LO    = (float*)alloc((size_t)NNODE*4*4);
  float* H1    = (float*)alloc((size_t)NNODE*HD_*4);
  float* H2    = (float*)alloc((size_t)NNODE*HD_*4);
  float* H3    = (float*)alloc((size_t)NNODE*HD_*4);
  float* Z1    = (float*)alloc((size_t)NNODE*1024*4);
  float* BIG   = (float*)alloc((size_t)NNODE*2304*4);  // XN / feat / z (phase-reused)

  float* XN = BIG;
  float* FT = BIG;
  float* Z  = BIG;
  float* out1 = (float*)d_out;
  float* out2 = out1 + (size_t)NNODE*NC_;

  // weight prep (idempotent, cheap)
  fold_transpose<<<(1024*2048+255)/256, 256, 0, stream>>>(W0, W0R0T, 2048, 1, 1024, 1024*2048);
  fold_transpose<<<( 256*2048+255)/256, 256, 0, stream>>>(R0, W0R0T + (size_t)1024*2048, 2048, 4, 256, 256*2048);
  fold_transpose<<<(1024*256 +255)/256, 256, 0, stream>>>(W1, W1R1T, 256, 1, 1024, 1024*256);
  fold_transpose<<<( 256*256 +255)/256, 256, 0, stream>>>(R1, W1R1T + (size_t)1024*256, 256, 4, 256, 256*256);
  fold_transpose<<<( 256*256 +255)/256, 256, 0, stream>>>(W2, W2T, 256, 1, 256, 256*256);
  fold_transpose<<<(1024*2304+255)/256, 256, 0, stream>>>(Wl1, WL1T, 2304, 1, 1024, 1024*2304);
  bfold_k<<<1, 256, 0, stream>>>(b0, BF0, 4, 256);
  bfold_k<<<1, 256, 0, stream>>>(b1, BF1, 4, 256);

  // graph construction
  rownorm_k<<<NNODE, 256, 0, stream>>>(x, XN);
  gemm_nt<2><<<dim3(64,64), 256, 0, stream>>>(XN, XN, nullptr, MASK,
      NNODE, NNODE, FIND, FIND, FIND, 0, nullptr, THRESH_);

  // ---- GAT layer 0 ----
  gemm_nt<0><<<dim3(20,64), 256, 0, stream>>>(x, W0R0T, FT, nullptr,
      NNODE, 1280, FIND, FIND, FIND, 1280, nullptr, 0.f);
  el_er_k<4><<<NNODE, 256, 0, stream>>>(FT, 1280, al0, ar0, EL, ER);
  stats_k<4><<<NNODE, 256, 0, stream>>>(MASK, EL, ER, MO, LO);
  agg_k<4,true><<<NNODE, 256, 0, stream>>>(FT, 1280, MASK, EL, ER, MO, LO,
      FT + 1024, 1280, BF0, H1);

  // ---- GAT layer 1 ----
  gemm_nt<0><<<dim3(20,64), 256, 0, stream>>>(H1, W1R1T, FT, nullptr,
      NNODE, 1280, 256, 256, 256, 1280, nullptr, 0.f);
  el_er_k<4><<<NNODE, 256, 0, stream>>>(FT, 1280, al1, ar1, EL, ER);
  stats_k<4><<<NNODE, 256, 0, stream>>>(MASK, EL, ER, MO, LO);
  agg_k<4,true><<<NNODE, 256, 0, stream>>>(FT, 1280, MASK, EL, ER, MO, LO,
      FT + 1024, 1280, BF1, H2);

  // ---- GAT layer 2 (1 head, identity residual, no relu) ----
  gemm_nt<0><<<dim3(4,64), 256, 0, stream>>>(H2, W2T, FT, nullptr,
      NNODE, 256, 256, 256, 256, 256, nullptr, 0.f);
  el_er_k<1><<<NNODE, 256, 0, stream>>>(FT, 256, al2, ar2, EL, ER);
  stats_k<1><<<NNODE, 256, 0, stream>>>(MASK, EL, ER, MO, LO);
  agg_k<1,false><<<NNODE, 256, 0, stream>>>(FT, 256, MASK, EL, ER, MO, LO,
      H2, 256, b2, H3);

  // ---- MLP heads ----
  concat_k<<<(NNODE*2304+255)/256, 256, 0, stream>>>(x, H3, Z);
  gemm_nt<1><<<dim3(16,64), 256, 0, stream>>>(Z, WL1T, Z1, nullptr,
      NNODE, 1024, 2304, 2304, 2304, 1024, bl1, 0.01f);
  head_k<<<NNODE, 256, 0, stream>>>(Z1, 1024, Wc1, bc1, out1);
  head_k<<<NNODE, 256, 0, stream>>>(x, FIND, Wc2, bc2, out2);
}

// Round 2
// 1761.477 us; speedup vs baseline: 1.1536x; 1.1536x over previous
//
#include <hip/hip_runtime.h>
#include <cstdint>
#include <cstddef>

#define NNODE 4096
#define FIND  2048
#define HD_   256
#define NC_   10
#define THRESH_ 0.05f
#define BKP 40   // padded LDS row length (bf16 elems): 80B stride -> 2-way bank alias (free)

typedef unsigned long long u64;
typedef __attribute__((ext_vector_type(8))) short bf16x8;
typedef __attribute__((ext_vector_type(4))) float f32x4;

// ---------- bf16 split helpers ----------
__device__ inline unsigned short f2bf_rne(float f){
  unsigned u = __builtin_bit_cast(unsigned, f);
  unsigned r = u + 0x7FFFu + ((u >> 16) & 1u);
  return (unsigned short)(r >> 16);
}
__device__ inline float bf2f(unsigned short h){
  unsigned u = ((unsigned)h) << 16;
  return __builtin_bit_cast(float, u);
}

// ---------- row normalize -> hi/lo bf16 ----------
__global__ void rownorm_bf(const float* __restrict__ x,
                           unsigned short* __restrict__ oh, unsigned short* __restrict__ ol){
  int row = blockIdx.x; int t = threadIdx.x;
  const float4* xr = reinterpret_cast<const float4*>(x + (size_t)row*FIND);
  float s = 0.f;
  #pragma unroll
  for (int i = 0; i < FIND/4/256; ++i){
    float4 v = xr[t + i*256];
    s += v.x*v.x + v.y*v.y + v.z*v.z + v.w*v.w;
  }
  #pragma unroll
  for (int o = 32; o > 0; o >>= 1) s += __shfl_down(s, o);
  __shared__ float red[4];
  __shared__ float invn;
  if ((t & 63) == 0) red[t >> 6] = s;
  __syncthreads();
  if (t == 0) invn = rsqrtf(red[0] + red[1] + red[2] + red[3]);
  __syncthreads();
  float inv = invn;
  #pragma unroll
  for (int i = 0; i < FIND/4/256; ++i){
    float4 v = xr[t + i*256];
    float a[4] = {v.x*inv, v.y*inv, v.z*inv, v.w*inv};
    ushort4 hv, lv;
    unsigned short* hp = &hv.x; unsigned short* lp = &lv.x;
    #pragma unroll
    for (int j = 0; j < 4; ++j){
      unsigned short h = f2bf_rne(a[j]);
      hp[j] = h; lp[j] = f2bf_rne(a[j] - bf2f(h));
    }
    size_t off = (size_t)row*FIND + (t + i*256)*4;
    *reinterpret_cast<ushort4*>(oh + off) = hv;
    *reinterpret_cast<ushort4*>(ol + off) = lv;
  }
}

// ---------- fp32 -> hi/lo bf16 (vectorized) ----------
__global__ void f2bf_k(const float* __restrict__ in, unsigned short* __restrict__ oh,
                       unsigned short* __restrict__ ol, int n4){
  int idx = blockIdx.x*256 + threadIdx.x;
  if (idx >= n4) return;
  float4 v = reinterpret_cast<const float4*>(in)[idx];
  float a[4] = {v.x, v.y, v.z, v.w};
  ushort4 hv, lv;
  unsigned short* hp = &hv.x; unsigned short* lp = &lv.x;
  #pragma unroll
  for (int j = 0; j < 4; ++j){
    unsigned short h = f2bf_rne(a[j]);
    hp[j] = h; lp[j] = f2bf_rne(a[j] - bf2f(h));
  }
  reinterpret_cast<ushort4*>(oh)[idx] = hv;
  reinterpret_cast<ushort4*>(ol)[idx] = lv;
}

// ---------- weight prep: R [K, H*F] -> outT [F, K] (sum over H), hi/lo bf16 ----------
__global__ void fold_bf(const float* __restrict__ R, unsigned short* __restrict__ oh,
                        unsigned short* __restrict__ ol, int K, int H, int F, int total){
  int idx = blockIdx.x*256 + threadIdx.x;
  if (idx >= total) return;
  int k = idx % K, f = idx / K;
  float s = 0.f;
  for (int h = 0; h < H; ++h) s += R[(size_t)k*(H*F) + (size_t)h*F + f];
  unsigned short hv = f2bf_rne(s);
  oh[(size_t)f*K + k] = hv;
  ol[(size_t)f*K + k] = f2bf_rne(s - bf2f(hv));
}

__global__ void bfold_k(const float* __restrict__ b, float* __restrict__ out, int H, int F){
  int f = threadIdx.x;
  if (f < F){
    float s = 0.f;
    for (int h = 0; h < H; ++h) s += b[h*F + f];
    out[f] = s;
  }
}

// ---------- split-bf16 MFMA NT GEMM: C[M,N] = A[M,K] * B[N,K]^T ----------
// EPI: 0 = store C; 2 = bitpack (val > param) into Mk; 3 = C += acc, +bias, leaky(param)
template<int EPI>
__launch_bounds__(256, 2)
__global__ void gemm_bf(const unsigned short* __restrict__ Ah, const unsigned short* __restrict__ Al,
                        const unsigned short* __restrict__ Bh, const unsigned short* __restrict__ Bl,
                        float* __restrict__ C, u64* __restrict__ Mk,
                        int K, int lda, int ldb, int ldc, int maskld,
                        const float* __restrict__ bias, float param){
  __shared__ unsigned short smem[4*128*BKP];
  unsigned short* sAh = smem;
  unsigned short* sAl = smem + 128*BKP;
  unsigned short* sBh = smem + 2*128*BKP;
  unsigned short* sBl = smem + 3*128*BKP;
  const int t = threadIdx.x;
  const int lane = t & 63, w = t >> 6;
  const int wr = w >> 1, wc = w & 1;
  const int l15 = lane & 15, lg = lane >> 4;
  const int row0 = blockIdx.y*128, col0 = blockIdx.x*128;
  const int sr = t >> 2, sc = (t & 3)*8;   // staging: thread covers rows sr, sr+64, 8 elems at sc

  f32x4 acc[4][4] = {};
  uint4 ra_h[2], ra_l[2], rb_h[2], rb_l[2];

  const int nk = K >> 5;
  // prologue load (k-tile 0)
  #pragma unroll
  for (int it = 0; it < 2; ++it){
    size_t ao = (size_t)(row0 + sr + it*64)*lda + sc;
    size_t bo = (size_t)(col0 + sr + it*64)*ldb + sc;
    ra_h[it] = *reinterpret_cast<const uint4*>(Ah + ao);
    ra_l[it] = *reinterpret_cast<const uint4*>(Al + ao);
    rb_h[it] = *reinterpret_cast<const uint4*>(Bh + bo);
    rb_l[it] = *reinterpret_cast<const uint4*>(Bl + bo);
  }

  for (int kt = 0; kt < nk; ++kt){
    __syncthreads();   // prev compute done before overwrite
    #pragma unroll
    for (int it = 0; it < 2; ++it){
      int so = (sr + it*64)*BKP + sc;
      *reinterpret_cast<uint4*>(sAh + so) = ra_h[it];
      *reinterpret_cast<uint4*>(sAl + so) = ra_l[it];
      *reinterpret_cast<uint4*>(sBh + so) = rb_h[it];
      *reinterpret_cast<uint4*>(sBl + so) = rb_l[it];
    }
    __syncthreads();
    if (kt + 1 < nk){
      size_t ko = (size_t)(kt + 1) << 5;
      #pragma unroll
      for (int it = 0; it < 2; ++it){
        size_t ao = (size_t)(row0 + sr + it*64)*lda + ko + sc;
        size_t bo = (size_t)(col0 + sr + it*64)*ldb + ko + sc;
        ra_h[it] = *reinterpret_cast<const uint4*>(Ah + ao);
        ra_l[it] = *reinterpret_cast<const uint4*>(Al + ao);
        rb_h[it] = *reinterpret_cast<const uint4*>(Bh + bo);
        rb_l[it] = *reinterpret_cast<const uint4*>(Bl + bo);
      }
    }
    // fragments
    bf16x8 fa_h[4], fa_l[4], fb_h[4], fb_l[4];
    #pragma unroll
    for (int i = 0; i < 4; ++i){
      int ao = (wr*64 + i*16 + l15)*BKP + lg*8;
      int bo = (wc*64 + i*16 + l15)*BKP + lg*8;
      fa_h[i] = *reinterpret_cast<const bf16x8*>(sAh + ao);
      fa_l[i] = *reinterpret_cast<const bf16x8*>(sAl + ao);
      fb_h[i] = *reinterpret_cast<const bf16x8*>(sBh + bo);
      fb_l[i] = *reinterpret_cast<const bf16x8*>(sBl + bo);
    }
    #pragma unroll
    for (int i = 0; i < 4; ++i)
      #pragma unroll
      for (int j = 0; j < 4; ++j){
        acc[i][j] = __builtin_amdgcn_mfma_f32_16x16x32_bf16(fa_h[i], fb_h[j], acc[i][j], 0, 0, 0);
        acc[i][j] = __builtin_amdgcn_mfma_f32_16x16x32_bf16(fa_h[i], fb_l[j], acc[i][j], 0, 0, 0);
        acc[i][j] = __builtin_amdgcn_mfma_f32_16x16x32_bf16(fa_l[i], fb_h[j], acc[i][j], 0, 0, 0);
      }
  }

  if (EPI == 2){
    // bitpack: wave (wr,wc) covers rows wr*64.., cols wc*64..+63 = one u64 word per row
    #pragma unroll
    for (int i = 0; i < 4; ++i){
      #pragma unroll
      for (int r = 0; r < 4; ++r){
        u64 bits = 0ull;
        #pragma unroll
        for (int j = 0; j < 4; ++j)
          if (acc[i][j][r] > param) bits |= 1ull << (j*16 + l15);
        #pragma unroll
        for (int m = 1; m <= 8; m <<= 1) bits |= __shfl_xor(bits, m);
        if (l15 == 0){
          int gr = row0 + wr*64 + i*16 + lg*4 + r;
          Mk[(size_t)gr*maskld + (col0 >> 6) + wc] = bits;
        }
      }
    }
  } else {
    #pragma unroll
    for (int i = 0; i < 4; ++i){
      int gr = row0 + wr*64 + i*16 + lg*4;
      #pragma unroll
      for (int j = 0; j < 4; ++j){
        int gc = col0 + wc*64 + j*16 + l15;
        #pragma unroll
        for (int r = 0; r < 4; ++r){
          float v = acc[i][j][r];
          size_t o = (size_t)(gr + r)*ldc + gc;
          if (EPI == 3){
            v += C[o] + bias[gc];
            v = v > 0.f ? v : param*v;
          }
          C[o] = v;
        }
      }
    }
  }
}

// ---------- el / er per node ----------
template<int H>
__global__ void el_er_k(const float* __restrict__ feat, int ldf,
                        const float* __restrict__ al, const float* __restrict__ ar,
                        float* __restrict__ el, float* __restrict__ er){
  int n = blockIdx.x, t = threadIdx.x;
  __shared__ float red[8];
  #pragma unroll
  for (int h = 0; h < H; ++h){
    float v = feat[(size_t)n*ldf + h*HD_ + t];
    float a = v * al[h*HD_ + t];
    float b = v * ar[h*HD_ + t];
    #pragma unroll
    for (int o = 32; o > 0; o >>= 1){ a += __shfl_down(a, o); b += __shfl_down(b, o); }
    if ((t & 63) == 0){ red[t >> 6] = a; red[4 + (t >> 6)] = b; }
    __syncthreads();
    if (t == 0){
      el[n*H + h] = red[0] + red[1] + red[2] + red[3];
      er[n*H + h] = red[4] + red[5] + red[6] + red[7];
    }
    __syncthreads();
  }
}

// ---------- softmax stats (max, denom) per dst ----------
template<int H>
__global__ void stats_k(const u64* __restrict__ Mk,
                        const float* __restrict__ el, const float* __restrict__ er,
                        float* __restrict__ mo, float* __restrict__ lo){
  int d = blockIdx.x, t = threadIdx.x;
  float erd[H], mx[H];
  #pragma unroll
  for (int h = 0; h < H; ++h){ erd[h] = er[d*H + h]; mx[h] = -1e30f; }
  for (int s = t; s < NNODE; s += 256){
    u64 w = Mk[(size_t)d*64 + (s >> 6)];
    if ((w >> (s & 63)) & 1ull){
      #pragma unroll
      for (int h = 0; h < H; ++h){
        float e = erd[h] + el[s*H + h];
        e = e > 0.f ? e : 0.2f*e;
        mx[h] = fmaxf(mx[h], e);
      }
    }
  }
  __shared__ float red[H*4];
  __shared__ float mfin[H];
  #pragma unroll
  for (int h = 0; h < H; ++h){
    float v = mx[h];
    #pragma unroll
    for (int o = 32; o > 0; o >>= 1) v = fmaxf(v, __shfl_down(v, o));
    if ((t & 63) == 0) red[h*4 + (t >> 6)] = v;
  }
  __syncthreads();
  if (t == 0){
    #pragma unroll
    for (int h = 0; h < H; ++h)
      mfin[h] = fmaxf(fmaxf(red[h*4+0], red[h*4+1]), fmaxf(red[h*4+2], red[h*4+3]));
  }
  __syncthreads();
  float sm[H];
  #pragma unroll
  for (int h = 0; h < H; ++h) sm[h] = 0.f;
  for (int s = t; s < NNODE; s += 256){
    u64 w = Mk[(size_t)d*64 + (s >> 6)];
    if ((w >> (s & 63)) & 1ull){
      #pragma unroll
      for (int h = 0; h < H; ++h){
        float e = erd[h] + el[s*H + h];
        e = e > 0.f ? e : 0.2f*e;
        sm[h] += __expf(e - mfin[h]);
      }
    }
  }
  __syncthreads();
  #pragma unroll
  for (int h = 0; h < H; ++h){
    float v = sm[h];
    #pragma unroll
    for (int o = 32; o > 0; o >>= 1) v += __shfl_down(v, o);
    if ((t & 63) == 0) red[h*4 + (t >> 6)] = v;
  }
  __syncthreads();
  if (t == 0){
    #pragma unroll
    for (int h = 0; h < H; ++h){
      mo[d*H + h] = mfin[h];
      lo[d*H + h] = red[h*4+0] + red[h*4+1] + red[h*4+2] + red[h*4+3];
    }
  }
}

// ---------- aggregation ----------
template<int H, bool RELU>
__global__ void agg_k(const float* __restrict__ feat, int ldf,
                      const u64* __restrict__ Mk,
                      const float* __restrict__ el, const float* __restrict__ er,
                      const float* __restrict__ mo, const float* __restrict__ lo,
                      const float* __restrict__ res, int ldres,
                      const float* __restrict__ bias,
                      float* __restrict__ out){
  int d = blockIdx.x, t = threadIdx.x;
  float erd[H], md[H], li[H], acc[H];
  #pragma unroll
  for (int h = 0; h < H; ++h){
    erd[h] = er[d*H + h];
    md[h]  = mo[d*H + h];
    li[h]  = 1.f / lo[d*H + h];
    acc[h] = 0.f;
  }
  for (int w = 0; w < 64; ++w){
    u64 bits = Mk[(size_t)d*64 + w];
    while (bits){
      int b = __builtin_ctzll(bits);
      bits &= bits - 1ull;
      int s = w*64 + b;
      #pragma unroll
      for (int h = 0; h < H; ++h){
        float e = erd[h] + el[s*H + h];
        e = e > 0.f ? e : 0.2f*e;
        float wt = __expf(e - md[h]) * li[h];
        acc[h] += wt * feat[(size_t)s*ldf + h*HD_ + t];
      }
    }
  }
  float v = 0.f;
  #pragma unroll
  for (int h = 0; h < H; ++h) v += acc[h];
  v += res[(size_t)d*ldres + t];
  v += bias[t];
  if (RELU) v = fmaxf(v, 0.f);
  out[(size_t)d*HD_ + t] = v;
}

// ---------- classifier head ----------
__global__ void head_k(const float* __restrict__ A, int K, const float* __restrict__ W,
                       const float* __restrict__ b, float* __restrict__ out){
  int row = blockIdx.x, t = threadIdx.x;
  float p[NC_];
  #pragma unroll
  for (int j = 0; j < NC_; ++j) p[j] = 0.f;
  for (int k = t; k < K; k += 256){
    float a = A[(size_t)row*K + k];
    #pragma unroll
    for (int j = 0; j < NC_; ++j) p[j] += a * W[k*NC_ + j];
  }
  #pragma unroll
  for (int j = 0; j < NC_; ++j){
    #pragma unroll
    for (int o = 32; o > 0; o >>= 1) p[j] += __shfl_down(p[j], o);
  }
  __shared__ float red[4][NC_];
  if ((t & 63) == 0){
    #pragma unroll
    for (int j = 0; j < NC_; ++j) red[t >> 6][j] = p[j];
  }
  __syncthreads();
  if (t < NC_)
    out[(size_t)row*NC_ + t] = red[0][t] + red[1][t] + red[2][t] + red[3][t] + b[t];
}

// ---------- launch ----------
extern "C" void kernel_launch(void* const* d_in, const int* in_sizes, int n_in,
                              void* d_out, int out_size, void* d_ws, size_t ws_size,
                              hipStream_t stream){
  const float* x   = (const float*)d_in[0];
  const float* W0  = (const float*)d_in[1];
  const float* al0 = (const float*)d_in[2];
  const float* ar0 = (const float*)d_in[3];
  const float* b0  = (const float*)d_in[4];
  const float* R0  = (const float*)d_in[5];
  const float* W1  = (const float*)d_in[6];
  const float* al1 = (const float*)d_in[7];
  const float* ar1 = (const float*)d_in[8];
  const float* b1  = (const float*)d_in[9];
  const float* R1  = (const float*)d_in[10];
  const float* W2  = (const float*)d_in[11];
  const float* al2 = (const float*)d_in[12];
  const float* ar2 = (const float*)d_in[13];
  const float* b2  = (const float*)d_in[14];
  const float* Wl1 = (const float*)d_in[15];
  const float* bl1 = (const float*)d_in[16];
  const float* Wc1 = (const float*)d_in[17];
  const float* bc1 = (const float*)d_in[18];
  const float* Wc2 = (const float*)d_in[19];
  const float* bc2 = (const float*)d_in[20];
  (void)in_sizes; (void)n_in; (void)out_size; (void)ws_size;

  char* ws = (char*)d_ws;
  size_t off = 0;
  auto alloc = [&](size_t bytes)->char*{
    char* p = ws + off; off += (bytes + 255) & ~(size_t)255; return p;
  };
  typedef unsigned short us;
  u64* MASK = (u64*)alloc((size_t)NNODE*64*8);
  us* W0h = (us*)alloc((size_t)1280*2048*2);  us* W0l = (us*)alloc((size_t)1280*2048*2);
  us* W1h = (us*)alloc((size_t)1280*256*2);   us* W1l = (us*)alloc((size_t)1280*256*2);
  us* W2h = (us*)alloc((size_t)256*256*2);    us* W2l = (us*)alloc((size_t)256*256*2);
  us* WLh = (us*)alloc((size_t)1024*2304*2);  us* WLl = (us*)alloc((size_t)1024*2304*2);
  float* BF0 = (float*)alloc(256*4);
  float* BF1 = (float*)alloc(256*4);
  float* EL  = (float*)alloc((size_t)NNODE*4*4);
  float* ER  = (float*)alloc((size_t)NNODE*4*4);
  float* MO  = (float*)alloc((size_t)NNODE*4*4);
  float* LO  = (float*)alloc((size_t)NNODE*4*4);
  us* XNh = (us*)alloc((size_t)NNODE*FIND*2);  // also reused as FT (fp32, 21MB < 32MB)
  us* XNl = (us*)alloc((size_t)NNODE*FIND*2);
  us* Xh  = (us*)alloc((size_t)NNODE*FIND*2);
  us* Xl  = (us*)alloc((size_t)NNODE*FIND*2);
  float* H1 = (float*)alloc((size_t)NNODE*HD_*4);
  float* H2 = (float*)alloc((size_t)NNODE*HD_*4);
  float* H3 = (float*)alloc((size_t)NNODE*HD_*4);
  us* H1h = (us*)alloc((size_t)NNODE*HD_*2);  us* H1l = (us*)alloc((size_t)NNODE*HD_*2);
  us* H2h = (us*)alloc((size_t)NNODE*HD_*2);  us* H2l = (us*)alloc((size_t)NNODE*HD_*2);
  us* H3h = (us*)alloc((size_t)NNODE*HD_*2);  us* H3l = (us*)alloc((size_t)NNODE*HD_*2);
  float* Z1 = (float*)alloc((size_t)NNODE*1024*4);

  float* FT = (float*)XNh;    // feat buffer, reused after Gram
  float* out1 = (float*)d_out;
  float* out2 = out1 + (size_t)NNODE*NC_;

  // ---- weight & input prep ----
  fold_bf<<<(1024*2048+255)/256, 256, 0, stream>>>(W0, W0h, W0l, 2048, 1, 1024, 1024*2048);
  fold_bf<<<( 256*2048+255)/256, 256, 0, stream>>>(R0, W0h + (size_t)1024*2048, W0l + (size_t)1024*2048, 2048, 4, 256, 256*2048);
  fold_bf<<<(1024*256 +255)/256, 256, 0, stream>>>(W1, W1h, W1l, 256, 1, 1024, 1024*256);
  fold_bf<<<( 256*256 +255)/256, 256, 0, stream>>>(R1, W1h + (size_t)1024*256, W1l + (size_t)1024*256, 256, 4, 256, 256*256);
  fold_bf<<<( 256*256 +255)/256, 256, 0, stream>>>(W2, W2h, W2l, 256, 1, 256, 256*256);
  fold_bf<<<(1024*2304+255)/256, 256, 0, stream>>>(Wl1, WLh, WLl, 2304, 1, 1024, 1024*2304);
  bfold_k<<<1, 256, 0, stream>>>(b0, BF0, 4, 256);
  bfold_k<<<1, 256, 0, stream>>>(b1, BF1, 4, 256);
  f2bf_k<<<(NNODE*FIND/4+255)/256, 256, 0, stream>>>(x, Xh, Xl, NNODE*FIND/4);
  rownorm_bf<<<NNODE, 256, 0, stream>>>(x, XNh, XNl);

  // ---- graph construction (Gram + threshold bitpack) ----
  gemm_bf<2><<<dim3(32,32), 256, 0, stream>>>(XNh, XNl, XNh, XNl, nullptr, MASK,
      FIND, FIND, FIND, 0, 64, nullptr, THRESH_);

  // ---- GAT layer 0 ----
  gemm_bf<0><<<dim3(10,32), 256, 0, stream>>>(Xh, Xl, W0h, W0l, FT, nullptr,
      FIND, FIND, FIND, 1280, 0, nullptr, 0.f);
  el_er_k<4><<<NNODE, 256, 0, stream>>>(FT, 1280, al0, ar0, EL, ER);
  stats_k<4><<<NNODE, 256, 0, stream>>>(MASK, EL, ER, MO, LO);
  agg_k<4,true><<<NNODE, 256, 0, stream>>>(FT, 1280, MASK, EL, ER, MO, LO,
      FT + 1024, 1280, BF0, H1);

  // ---- GAT layer 1 ----
  f2bf_k<<<(NNODE*HD_/4+255)/256, 256, 0, stream>>>(H1, H1h, H1l, NNODE*HD_/4);
  gemm_bf<0><<<dim3(10,32), 256, 0, stream>>>(H1h, H1l, W1h, W1l, FT, nullptr,
      256, 256, 256, 1280, 0, nullptr, 0.f);
  el_er_k<4><<<NNODE, 256, 0, stream>>>(FT, 1280, al1, ar1, EL, ER);
  stats_k<4><<<NNODE, 256, 0, stream>>>(MASK, EL, ER, MO, LO);
  agg_k<4,true><<<NNODE, 256, 0, stream>>>(FT, 1280, MASK, EL, ER, MO, LO,
      FT + 1024, 1280, BF1, H2);

  // ---- GAT layer 2 (1 head, identity residual, no relu) ----
  f2bf_k<<<(NNODE*HD_/4+255)/256, 256, 0, stream>>>(H2, H2h, H2l, NNODE*HD_/4);
  gemm_bf<0><<<dim3(2,32), 256, 0, stream>>>(H2h, H2l, W2h, W2l, FT, nullptr,
      256, 256, 256, 256, 0, nullptr, 0.f);
  el_er_k<1><<<NNODE, 256, 0, stream>>>(FT, 256, al2, ar2, EL, ER);
  stats_k<1><<<NNODE, 256, 0, stream>>>(MASK, EL, ER, MO, LO);
  agg_k<1,false><<<NNODE, 256, 0, stream>>>(FT, 256, MASK, EL, ER, MO, LO,
      H2, 256, b2, H3);

  // ---- MLP: z = [x, h3]; Z1 = leaky(z @ Wl1 + bl1) via K-split accumulate ----
  f2bf_k<<<(NNODE*HD_/4+255)/256, 256, 0, stream>>>(H3, H3h, H3l, NNODE*HD_/4);
  gemm_bf<0><<<dim3(8,32), 256, 0, stream>>>(Xh, Xl, WLh, WLl, Z1, nullptr,
      FIND, FIND, 2304, 1024, 0, nullptr, 0.f);
  gemm_bf<3><<<dim3(8,32), 256, 0, stream>>>(H3h, H3l, WLh + 2048, WLl + 2048, Z1, nullptr,
      256, 256, 2304, 1024, 0, bl1, 0.01f);

  head_k<<<NNODE, 256, 0, stream>>>(Z1, 1024, Wc1, bc1, out1);
  head_k<<<NNODE, 256, 0, stream>>>(x, FIND, Wc2, bc2, out2);
}

// Round 3
// 871.714 us; speedup vs baseline: 2.3310x; 2.0207x over previous
//
#include <hip/hip_runtime.h>
#include <cstdint>
#include <cstddef>

#define NNODE 4096
#define FIND  2048
#define HD_   256
#define NC_   10
#define THRESH_ 0.05f

typedef unsigned long long u64;
typedef __attribute__((ext_vector_type(8))) short bf16x8;
typedef __attribute__((ext_vector_type(4))) float f32x4;

// ---------- bf16 split helpers ----------
__device__ inline unsigned short f2bf_rne(float f){
  unsigned u = __builtin_bit_cast(unsigned, f);
  unsigned r = u + 0x7FFFu + ((u >> 16) & 1u);
  return (unsigned short)(r >> 16);
}
__device__ inline float bf2f(unsigned short h){
  unsigned u = ((unsigned)h) << 16;
  return __builtin_bit_cast(float, u);
}

// async global->LDS, 16B per lane; lds dest is wave-uniform base (+lane*16 by HW)
__device__ __forceinline__ void gld16(const void* g, void* l){
  __builtin_amdgcn_global_load_lds(
      (const __attribute__((address_space(1))) unsigned int*)g,
      (__attribute__((address_space(3))) unsigned int*)l, 16, 0, 0);
}

// ---------- row normalize -> hi/lo bf16 ----------
__global__ void rownorm_bf(const float* __restrict__ x,
                           unsigned short* __restrict__ oh, unsigned short* __restrict__ ol){
  int row = blockIdx.x; int t = threadIdx.x;
  const float4* xr = reinterpret_cast<const float4*>(x + (size_t)row*FIND);
  float s = 0.f;
  #pragma unroll
  for (int i = 0; i < FIND/4/256; ++i){
    float4 v = xr[t + i*256];
    s += v.x*v.x + v.y*v.y + v.z*v.z + v.w*v.w;
  }
  #pragma unroll
  for (int o = 32; o > 0; o >>= 1) s += __shfl_down(s, o);
  __shared__ float red[4];
  __shared__ float invn;
  if ((t & 63) == 0) red[t >> 6] = s;
  __syncthreads();
  if (t == 0) invn = rsqrtf(red[0] + red[1] + red[2] + red[3]);
  __syncthreads();
  float inv = invn;
  #pragma unroll
  for (int i = 0; i < FIND/4/256; ++i){
    float4 v = xr[t + i*256];
    float a[4] = {v.x*inv, v.y*inv, v.z*inv, v.w*inv};
    ushort4 hv, lv;
    unsigned short* hp = &hv.x; unsigned short* lp = &lv.x;
    #pragma unroll
    for (int j = 0; j < 4; ++j){
      unsigned short h = f2bf_rne(a[j]);
      hp[j] = h; lp[j] = f2bf_rne(a[j] - bf2f(h));
    }
    size_t off = (size_t)row*FIND + (t + i*256)*4;
    *reinterpret_cast<ushort4*>(oh + off) = hv;
    *reinterpret_cast<ushort4*>(ol + off) = lv;
  }
}

// ---------- fp32 -> hi/lo bf16 (vectorized) ----------
__global__ void f2bf_k(const float* __restrict__ in, unsigned short* __restrict__ oh,
                       unsigned short* __restrict__ ol, int n4){
  int idx = blockIdx.x*256 + threadIdx.x;
  if (idx >= n4) return;
  float4 v = reinterpret_cast<const float4*>(in)[idx];
  float a[4] = {v.x, v.y, v.z, v.w};
  ushort4 hv, lv;
  unsigned short* hp = &hv.x; unsigned short* lp = &lv.x;
  #pragma unroll
  for (int j = 0; j < 4; ++j){
    unsigned short h = f2bf_rne(a[j]);
    hp[j] = h; lp[j] = f2bf_rne(a[j] - bf2f(h));
  }
  reinterpret_cast<ushort4*>(oh)[idx] = hv;
  reinterpret_cast<ushort4*>(ol)[idx] = lv;
}

// ---------- weight prep: R [K, H*F] -> outT [F, K] (sum over H), hi/lo bf16 ----------
__global__ void fold_bf(const float* __restrict__ R, unsigned short* __restrict__ oh,
                        unsigned short* __restrict__ ol, int K, int H, int F, int total){
  int idx = blockIdx.x*256 + threadIdx.x;
  if (idx >= total) return;
  int k = idx % K, f = idx / K;
  float s = 0.f;
  for (int h = 0; h < H; ++h) s += R[(size_t)k*(H*F) + (size_t)h*F + f];
  unsigned short hv = f2bf_rne(s);
  oh[(size_t)f*K + k] = hv;
  ol[(size_t)f*K + k] = f2bf_rne(s - bf2f(hv));
}

__global__ void bfold_k(const float* __restrict__ b, float* __restrict__ out, int H, int F){
  int f = threadIdx.x;
  if (f < F){
    float s = 0.f;
    for (int h = 0; h < H; ++h) s += b[h*F + f];
    out[f] = s;
  }
}

// ---------- split-bf16 MFMA NT GEMM (m97 structure): C[M,N] = A[M,K] * B[N,K]^T ----------
// linear LDS [128][32] per operand buffer, global_load_lds staging, 2-barrier K-loop.
// EPI: 0 = store C; 2 = bitpack (val > param) into Mk; 3 = C += acc, +bias, leaky(param)
template<int EPI>
__global__ void gemm_bf(const unsigned short* __restrict__ Ah, const unsigned short* __restrict__ Al,
                        const unsigned short* __restrict__ Bh, const unsigned short* __restrict__ Bl,
                        float* __restrict__ C, u64* __restrict__ Mk,
                        int K, int lda, int ldb, int ldc, int maskld, int gridx,
                        const float* __restrict__ bias, float param){
  __shared__ unsigned short smem[4*128*32];
  unsigned short* sAh = smem;
  unsigned short* sAl = smem + 4096;
  unsigned short* sBh = smem + 8192;
  unsigned short* sBl = smem + 12288;
  const int t = threadIdx.x, lane = t & 63, w = t >> 6;
  const int wr = w >> 1, wc = w & 1, l15 = lane & 15, lg = lane >> 4;

  // XCD-aware swizzle (bijective since all our grids are %8==0)
  int nwg = gridDim.x, bid = blockIdx.x;
  int wg = ((nwg & 7) == 0) ? ((bid & 7)*(nwg >> 3) + (bid >> 3)) : bid;
  int brow = wg / gridx, bcol = wg % gridx;
  const int row0 = brow*128, col0 = bcol*128;

  // staging: 8 chunks of 1KB per operand buffer; wave w stages chunks 2w, 2w+1.
  // chunk c covers rows 16c..16c+15; lane l -> row 16c + (l>>2), 16B piece (l&3).
  const int c0 = 2*w, c1 = 2*w + 1;
  const int rsub = lane >> 2, piece = lane & 3;
  const size_t ld2a = (size_t)lda*2, ld2b = (size_t)ldb*2;
  const size_t a0 = (size_t)(row0 + 16*c0 + rsub)*ld2a + piece*16;
  const size_t a1 = (size_t)(row0 + 16*c1 + rsub)*ld2a + piece*16;
  const size_t b0 = (size_t)(col0 + 16*c0 + rsub)*ld2b + piece*16;
  const size_t b1 = (size_t)(col0 + 16*c1 + rsub)*ld2b + piece*16;
  const char* pA0h = (const char*)Ah + a0;  const char* pA1h = (const char*)Ah + a1;
  const char* pA0l = (const char*)Al + a0;  const char* pA1l = (const char*)Al + a1;
  const char* pB0h = (const char*)Bh + b0;  const char* pB1h = (const char*)Bh + b1;
  const char* pB0l = (const char*)Bl + b0;  const char* pB1l = (const char*)Bl + b1;
  char* lA0h = (char*)sAh + c0*1024;  char* lA1h = (char*)sAh + c1*1024;
  char* lA0l = (char*)sAl + c0*1024;  char* lA1l = (char*)sAl + c1*1024;
  char* lB0h = (char*)sBh + c0*1024;  char* lB1h = (char*)sBh + c1*1024;
  char* lB0l = (char*)sBl + c0*1024;  char* lB1l = (char*)sBl + c1*1024;

  f32x4 acc[4][4] = {};
  const int nk = K >> 5;
  for (int kt = 0; kt < nk; ++kt){
    __syncthreads();             // prev iter's fragment reads done
    gld16(pA0h, lA0h); gld16(pA1h, lA1h);
    gld16(pA0l, lA0l); gld16(pA1l, lA1l);
    gld16(pB0h, lB0h); gld16(pB1h, lB1h);
    gld16(pB0l, lB0l); gld16(pB1l, lB1l);
    pA0h += 64; pA1h += 64; pA0l += 64; pA1l += 64;
    pB0h += 64; pB1h += 64; pB0l += 64; pB1l += 64;
    __syncthreads();             // vmcnt(0)+barrier: all staged data visible
    bf16x8 fb_h[4], fb_l[4];
    #pragma unroll
    for (int j = 0; j < 4; ++j){
      int bo = (wc*64 + j*16 + l15)*32 + lg*8;
      fb_h[j] = *reinterpret_cast<const bf16x8*>(sBh + bo);
      fb_l[j] = *reinterpret_cast<const bf16x8*>(sBl + bo);
    }
    #pragma unroll
    for (int i = 0; i < 4; ++i){
      int ao = (wr*64 + i*16 + l15)*32 + lg*8;
      bf16x8 fah = *reinterpret_cast<const bf16x8*>(sAh + ao);
      bf16x8 fal = *reinterpret_cast<const bf16x8*>(sAl + ao);
      #pragma unroll
      for (int j = 0; j < 4; ++j){
        acc[i][j] = __builtin_amdgcn_mfma_f32_16x16x32_bf16(fah, fb_h[j], acc[i][j], 0, 0, 0);
        acc[i][j] = __builtin_amdgcn_mfma_f32_16x16x32_bf16(fah, fb_l[j], acc[i][j], 0, 0, 0);
        acc[i][j] = __builtin_amdgcn_mfma_f32_16x16x32_bf16(fal, fb_h[j], acc[i][j], 0, 0, 0);
      }
    }
  }

  if (EPI == 2){
    // bitpack: wave (wr,wc) covers rows wr*64.., cols wc*64..+63 = one u64 word per row
    #pragma unroll
    for (int i = 0; i < 4; ++i){
      #pragma unroll
      for (int r = 0; r < 4; ++r){
        u64 bits = 0ull;
        #pragma unroll
        for (int j = 0; j < 4; ++j)
          if (acc[i][j][r] > param) bits |= 1ull << (j*16 + l15);
        #pragma unroll
        for (int m = 1; m <= 8; m <<= 1) bits |= __shfl_xor(bits, m);
        if (l15 == 0){
          int gr = row0 + wr*64 + i*16 + lg*4 + r;
          Mk[(size_t)gr*maskld + (col0 >> 6) + wc] = bits;
        }
      }
    }
  } else {
    #pragma unroll
    for (int i = 0; i < 4; ++i){
      int gr = row0 + wr*64 + i*16 + lg*4;
      #pragma unroll
      for (int j = 0; j < 4; ++j){
        int gc = col0 + wc*64 + j*16 + l15;
        #pragma unroll
        for (int r = 0; r < 4; ++r){
          float v = acc[i][j][r];
          size_t o = (size_t)(gr + r)*ldc + gc;
          if (EPI == 3){
            v += C[o] + bias[gc];
            v = v > 0.f ? v : param*v;
          }
          C[o] = v;
        }
      }
    }
  }
}

// ---------- el / er per node ----------
template<int H>
__global__ void el_er_k(const float* __restrict__ feat, int ldf,
                        const float* __restrict__ al, const float* __restrict__ ar,
                        float* __restrict__ el, float* __restrict__ er){
  int n = blockIdx.x, t = threadIdx.x;
  __shared__ float red[8];
  #pragma unroll
  for (int h = 0; h < H; ++h){
    float v = feat[(size_t)n*ldf + h*HD_ + t];
    float a = v * al[h*HD_ + t];
    float b = v * ar[h*HD_ + t];
    #pragma unroll
    for (int o = 32; o > 0; o >>= 1){ a += __shfl_down(a, o); b += __shfl_down(b, o); }
    if ((t & 63) == 0){ red[t >> 6] = a; red[4 + (t >> 6)] = b; }
    __syncthreads();
    if (t == 0){
      el[n*H + h] = red[0] + red[1] + red[2] + red[3];
      er[n*H + h] = red[4] + red[5] + red[6] + red[7];
    }
    __syncthreads();
  }
}

// ---------- softmax stats (max, denom) per dst ----------
template<int H>
__global__ void stats_k(const u64* __restrict__ Mk,
                        const float* __restrict__ el, const float* __restrict__ er,
                        float* __restrict__ mo, float* __restrict__ lo){
  int d = blockIdx.x, t = threadIdx.x;
  float erd[H], mx[H];
  #pragma unroll
  for (int h = 0; h < H; ++h){ erd[h] = er[d*H + h]; mx[h] = -1e30f; }
  for (int s = t; s < NNODE; s += 256){
    u64 w = Mk[(size_t)d*64 + (s >> 6)];
    if ((w >> (s & 63)) & 1ull){
      #pragma unroll
      for (int h = 0; h < H; ++h){
        float e = erd[h] + el[s*H + h];
        e = e > 0.f ? e : 0.2f*e;
        mx[h] = fmaxf(mx[h], e);
      }
    }
  }
  __shared__ float red[H*4];
  __shared__ float mfin[H];
  #pragma unroll
  for (int h = 0; h < H; ++h){
    float v = mx[h];
    #pragma unroll
    for (int o = 32; o > 0; o >>= 1) v = fmaxf(v, __shfl_down(v, o));
    if ((t & 63) == 0) red[h*4 + (t >> 6)] = v;
  }
  __syncthreads();
  if (t == 0){
    #pragma unroll
    for (int h = 0; h < H; ++h)
      mfin[h] = fmaxf(fmaxf(red[h*4+0], red[h*4+1]), fmaxf(red[h*4+2], red[h*4+3]));
  }
  __syncthreads();
  float sm[H];
  #pragma unroll
  for (int h = 0; h < H; ++h) sm[h] = 0.f;
  for (int s = t; s < NNODE; s += 256){
    u64 w = Mk[(size_t)d*64 + (s >> 6)];
    if ((w >> (s & 63)) & 1ull){
      #pragma unroll
      for (int h = 0; h < H; ++h){
        float e = erd[h] + el[s*H + h];
        e = e > 0.f ? e : 0.2f*e;
        sm[h] += __expf(e - mfin[h]);
      }
    }
  }
  __syncthreads();
  #pragma unroll
  for (int h = 0; h < H; ++h){
    float v = sm[h];
    #pragma unroll
    for (int o = 32; o > 0; o >>= 1) v += __shfl_down(v, o);
    if ((t & 63) == 0) red[h*4 + (t >> 6)] = v;
  }
  __syncthreads();
  if (t == 0){
    #pragma unroll
    for (int h = 0; h < H; ++h){
      mo[d*H + h] = mfin[h];
      lo[d*H + h] = red[h*4+0] + red[h*4+1] + red[h*4+2] + red[h*4+3];
    }
  }
}

// ---------- aggregation ----------
template<int H, bool RELU>
__global__ void agg_k(const float* __restrict__ feat, int ldf,
                      const u64* __restrict__ Mk,
                      const float* __restrict__ el, const float* __restrict__ er,
                      const float* __restrict__ mo, const float* __restrict__ lo,
                      const float* __restrict__ res, int ldres,
                      const float* __restrict__ bias,
                      float* __restrict__ out){
  int d = blockIdx.x, t = threadIdx.x;
  float erd[H], md[H], li[H], acc[H];
  #pragma unroll
  for (int h = 0; h < H; ++h){
    erd[h] = er[d*H + h];
    md[h]  = mo[d*H + h];
    li[h]  = 1.f / lo[d*H + h];
    acc[h] = 0.f;
  }
  for (int w = 0; w < 64; ++w){
    u64 bits = Mk[(size_t)d*64 + w];
    while (bits){
      int b = __builtin_ctzll(bits);
      bits &= bits - 1ull;
      int s = w*64 + b;
      #pragma unroll
      for (int h = 0; h < H; ++h){
        float e = erd[h] + el[s*H + h];
        e = e > 0.f ? e : 0.2f*e;
        float wt = __expf(e - md[h]) * li[h];
        acc[h] += wt * feat[(size_t)s*ldf + h*HD_ + t];
      }
    }
  }
  float v = 0.f;
  #pragma unroll
  for (int h = 0; h < H; ++h) v += acc[h];
  v += res[(size_t)d*ldres + t];
  v += bias[t];
  if (RELU) v = fmaxf(v, 0.f);
  out[(size_t)d*HD_ + t] = v;
}

// ---------- classifier head ----------
__global__ void head_k(const float* __restrict__ A, int K, const float* __restrict__ W,
                       const float* __restrict__ b, float* __restrict__ out){
  int row = blockIdx.x, t = threadIdx.x;
  float p[NC_];
  #pragma unroll
  for (int j = 0; j < NC_; ++j) p[j] = 0.f;
  for (int k = t; k < K; k += 256){
    float a = A[(size_t)row*K + k];
    #pragma unroll
    for (int j = 0; j < NC_; ++j) p[j] += a * W[k*NC_ + j];
  }
  #pragma unroll
  for (int j = 0; j < NC_; ++j){
    #pragma unroll
    for (int o = 32; o > 0; o >>= 1) p[j] += __shfl_down(p[j], o);
  }
  __shared__ float red[4][NC_];
  if ((t & 63) == 0){
    #pragma unroll
    for (int j = 0; j < NC_; ++j) red[t >> 6][j] = p[j];
  }
  __syncthreads();
  if (t < NC_)
    out[(size_t)row*NC_ + t] = red[0][t] + red[1][t] + red[2][t] + red[3][t] + b[t];
}

// ---------- launch ----------
extern "C" void kernel_launch(void* const* d_in, const int* in_sizes, int n_in,
                              void* d_out, int out_size, void* d_ws, size_t ws_size,
                              hipStream_t stream){
  const float* x   = (const float*)d_in[0];
  const float* W0  = (const float*)d_in[1];
  const float* al0 = (const float*)d_in[2];
  const float* ar0 = (const float*)d_in[3];
  const float* b0  = (const float*)d_in[4];
  const float* R0  = (const float*)d_in[5];
  const float* W1  = (const float*)d_in[6];
  const float* al1 = (const float*)d_in[7];
  const float* ar1 = (const float*)d_in[8];
  const float* b1  = (const float*)d_in[9];
  const float* R1  = (const float*)d_in[10];
  const float* W2  = (const float*)d_in[11];
  const float* al2 = (const float*)d_in[12];
  const float* ar2 = (const float*)d_in[13];
  const float* b2  = (const float*)d_in[14];
  const float* Wl1 = (const float*)d_in[15];
  const float* bl1 = (const float*)d_in[16];
  const float* Wc1 = (const float*)d_in[17];
  const float* bc1 = (const float*)d_in[18];
  const float* Wc2 = (const float*)d_in[19];
  const float* bc2 = (const float*)d_in[20];
  (void)in_sizes; (void)n_in; (void)out_size; (void)ws_size;

  char* ws = (char*)d_ws;
  size_t off = 0;
  auto alloc = [&](size_t bytes)->char*{
    char* p = ws + off; off += (bytes + 255) & ~(size_t)255; return p;
  };
  typedef unsigned short us;
  u64* MASK = (u64*)alloc((size_t)NNODE*64*8);
  us* W0h = (us*)alloc((size_t)1280*2048*2);  us* W0l = (us*)alloc((size_t)1280*2048*2);
  us* W1h = (us*)alloc((size_t)1280*256*2);   us* W1l = (us*)alloc((size_t)1280*256*2);
  us* W2h = (us*)alloc((size_t)256*256*2);    us* W2l = (us*)alloc((size_t)256*256*2);
  us* WLh = (us*)alloc((size_t)1024*2304*2);  us* WLl = (us*)alloc((size_t)1024*2304*2);
  float* BF0 = (float*)alloc(256*4);
  float* BF1 = (float*)alloc(256*4);
  float* EL  = (float*)alloc((size_t)NNODE*4*4);
  float* ER  = (float*)alloc((size_t)NNODE*4*4);
  float* MO  = (float*)alloc((size_t)NNODE*4*4);
  float* LO  = (float*)alloc((size_t)NNODE*4*4);
  us* XNh = (us*)alloc((size_t)NNODE*FIND*2);  // reused as FT (fp32, 21MB) after Gram
  us* XNl = (us*)alloc((size_t)NNODE*FIND*2);
  us* Xh  = (us*)alloc((size_t)NNODE*FIND*2);
  us* Xl  = (us*)alloc((size_t)NNODE*FIND*2);
  float* H1 = (float*)alloc((size_t)NNODE*HD_*4);
  float* H2 = (float*)alloc((size_t)NNODE*HD_*4);
  float* H3 = (float*)alloc((size_t)NNODE*HD_*4);
  us* H1h = (us*)alloc((size_t)NNODE*HD_*2);  us* H1l = (us*)alloc((size_t)NNODE*HD_*2);
  us* H2h = (us*)alloc((size_t)NNODE*HD_*2);  us* H2l = (us*)alloc((size_t)NNODE*HD_*2);
  us* H3h = (us*)alloc((size_t)NNODE*HD_*2);  us* H3l = (us*)alloc((size_t)NNODE*HD_*2);
  float* Z1 = (float*)alloc((size_t)NNODE*1024*4);

  float* FT = (float*)XNh;
  float* out1 = (float*)d_out;
  float* out2 = out1 + (size_t)NNODE*NC_;

  // ---- weight & input prep ----
  fold_bf<<<(1024*2048+255)/256, 256, 0, stream>>>(W0, W0h, W0l, 2048, 1, 1024, 1024*2048);
  fold_bf<<<( 256*2048+255)/256, 256, 0, stream>>>(R0, W0h + (size_t)1024*2048, W0l + (size_t)1024*2048, 2048, 4, 256, 256*2048);
  fold_bf<<<(1024*256 +255)/256, 256, 0, stream>>>(W1, W1h, W1l, 256, 1, 1024, 1024*256);
  fold_bf<<<( 256*256 +255)/256, 256, 0, stream>>>(R1, W1h + (size_t)1024*256, W1l + (size_t)1024*256, 256, 4, 256, 256*256);
  fold_bf<<<( 256*256 +255)/256, 256, 0, stream>>>(W2, W2h, W2l, 256, 1, 256, 256*256);
  fold_bf<<<(1024*2304+255)/256, 256, 0, stream>>>(Wl1, WLh, WLl, 2304, 1, 1024, 1024*2304);
  bfold_k<<<1, 256, 0, stream>>>(b0, BF0, 4, 256);
  bfold_k<<<1, 256, 0, stream>>>(b1, BF1, 4, 256);
  f2bf_k<<<(NNODE*FIND/4+255)/256, 256, 0, stream>>>(x, Xh, Xl, NNODE*FIND/4);
  rownorm_bf<<<NNODE, 256, 0, stream>>>(x, XNh, XNl);

  // ---- graph construction (Gram + threshold bitpack); grid 32x32 -> 1024 ----
  gemm_bf<2><<<1024, 256, 0, stream>>>(XNh, XNl, XNh, XNl, nullptr, MASK,
      FIND, FIND, FIND, 0, 64, 32, nullptr, THRESH_);

  // ---- GAT layer 0: [4096 x 1280] = x @ [W0|sumR0]^T ----
  gemm_bf<0><<<320, 256, 0, stream>>>(Xh, Xl, W0h, W0l, FT, nullptr,
      FIND, FIND, FIND, 1280, 0, 10, nullptr, 0.f);
  el_er_k<4><<<NNODE, 256, 0, stream>>>(FT, 1280, al0, ar0, EL, ER);
  stats_k<4><<<NNODE, 256, 0, stream>>>(MASK, EL, ER, MO, LO);
  agg_k<4,true><<<NNODE, 256, 0, stream>>>(FT, 1280, MASK, EL, ER, MO, LO,
      FT + 1024, 1280, BF0, H1);

  // ---- GAT layer 1 ----
  f2bf_k<<<(NNODE*HD_/4+255)/256, 256, 0, stream>>>(H1, H1h, H1l, NNODE*HD_/4);
  gemm_bf<0><<<320, 256, 0, stream>>>(H1h, H1l, W1h, W1l, FT, nullptr,
      256, 256, 256, 1280, 0, 10, nullptr, 0.f);
  el_er_k<4><<<NNODE, 256, 0, stream>>>(FT, 1280, al1, ar1, EL, ER);
  stats_k<4><<<NNODE, 256, 0, stream>>>(MASK, EL, ER, MO, LO);
  agg_k<4,true><<<NNODE, 256, 0, stream>>>(FT, 1280, MASK, EL, ER, MO, LO,
      FT + 1024, 1280, BF1, H2);

  // ---- GAT layer 2 (1 head, identity residual, no relu) ----
  f2bf_k<<<(NNODE*HD_/4+255)/256, 256, 0, stream>>>(H2, H2h, H2l, NNODE*HD_/4);
  gemm_bf<0><<<64, 256, 0, stream>>>(H2h, H2l, W2h, W2l, FT, nullptr,
      256, 256, 256, 256, 0, 2, nullptr, 0.f);
  el_er_k<1><<<NNODE, 256, 0, stream>>>(FT, 256, al2, ar2, EL, ER);
  stats_k<1><<<NNODE, 256, 0, stream>>>(MASK, EL, ER, MO, LO);
  agg_k<1,false><<<NNODE, 256, 0, stream>>>(FT, 256, MASK, EL, ER, MO, LO,
      H2, 256, b2, H3);

  // ---- MLP: Z1 = leaky([x,h3] @ Wl1 + bl1) via K-split accumulate ----
  f2bf_k<<<(NNODE*HD_/4+255)/256, 256, 0, stream>>>(H3, H3h, H3l, NNODE*HD_/4);
  gemm_bf<0><<<256, 256, 0, stream>>>(Xh, Xl, WLh, WLl, Z1, nullptr,
      FIND, FIND, 2304, 1024, 0, 8, nullptr, 0.f);
  gemm_bf<3><<<256, 256, 0, stream>>>(H3h, H3l, WLh + 2048, WLl + 2048, Z1, nullptr,
      256, 256, 2304, 1024, 0, 8, bl1, 0.01f);

  head_k<<<NNODE, 256, 0, stream>>>(Z1, 1024, Wc1, bc1, out1);
  head_k<<<NNODE, 256, 0, stream>>>(x, FIND, Wc2, bc2, out2);
}

// Round 4
// 826.552 us; speedup vs baseline: 2.4584x; 1.0546x over previous
//
#include <hip/hip_runtime.h>
#include <cstdint>
#include <cstddef>

#define NNODE 4096
#define FIND  2048
#define HD_   256
#define NC_   10
#define THRESH_ 0.05f

typedef unsigned long long u64;
typedef __attribute__((ext_vector_type(8))) short bf16x8;
typedef __attribute__((ext_vector_type(4))) float f32x4;

// ---------- bf16 split helpers ----------
__device__ inline unsigned short f2bf_rne(float f){
  unsigned u = __builtin_bit_cast(unsigned, f);
  unsigned r = u + 0x7FFFu + ((u >> 16) & 1u);
  return (unsigned short)(r >> 16);
}
__device__ inline float bf2f(unsigned short h){
  unsigned u = ((unsigned)h) << 16;
  return __builtin_bit_cast(float, u);
}

// async global->LDS, 16B per lane; lds dest is wave-uniform base (+lane*16 by HW)
__device__ __forceinline__ void gld16(const void* g, void* l){
  __builtin_amdgcn_global_load_lds(
      (const __attribute__((address_space(1))) unsigned int*)g,
      (__attribute__((address_space(3))) unsigned int*)l, 16, 0, 0);
}

// ---------- row normalize -> hi/lo bf16 ----------
__global__ void rownorm_bf(const float* __restrict__ x,
                           unsigned short* __restrict__ oh, unsigned short* __restrict__ ol){
  int row = blockIdx.x; int t = threadIdx.x;
  const float4* xr = reinterpret_cast<const float4*>(x + (size_t)row*FIND);
  float s = 0.f;
  #pragma unroll
  for (int i = 0; i < FIND/4/256; ++i){
    float4 v = xr[t + i*256];
    s += v.x*v.x + v.y*v.y + v.z*v.z + v.w*v.w;
  }
  #pragma unroll
  for (int o = 32; o > 0; o >>= 1) s += __shfl_down(s, o);
  __shared__ float red[4];
  __shared__ float invn;
  if ((t & 63) == 0) red[t >> 6] = s;
  __syncthreads();
  if (t == 0) invn = rsqrtf(red[0] + red[1] + red[2] + red[3]);
  __syncthreads();
  float inv = invn;
  #pragma unroll
  for (int i = 0; i < FIND/4/256; ++i){
    float4 v = xr[t + i*256];
    float a[4] = {v.x*inv, v.y*inv, v.z*inv, v.w*inv};
    ushort4 hv, lv;
    unsigned short* hp = &hv.x; unsigned short* lp = &lv.x;
    #pragma unroll
    for (int j = 0; j < 4; ++j){
      unsigned short h = f2bf_rne(a[j]);
      hp[j] = h; lp[j] = f2bf_rne(a[j] - bf2f(h));
    }
    size_t off = (size_t)row*FIND + (t + i*256)*4;
    *reinterpret_cast<ushort4*>(oh + off) = hv;
    *reinterpret_cast<ushort4*>(ol + off) = lv;
  }
}

// ---------- fp32 -> hi/lo bf16 (vectorized) ----------
__global__ void f2bf_k(const float* __restrict__ in, unsigned short* __restrict__ oh,
                       unsigned short* __restrict__ ol, int n4){
  int idx = blockIdx.x*256 + threadIdx.x;
  if (idx >= n4) return;
  float4 v = reinterpret_cast<const float4*>(in)[idx];
  float a[4] = {v.x, v.y, v.z, v.w};
  ushort4 hv, lv;
  unsigned short* hp = &hv.x; unsigned short* lp = &lv.x;
  #pragma unroll
  for (int j = 0; j < 4; ++j){
    unsigned short h = f2bf_rne(a[j]);
    hp[j] = h; lp[j] = f2bf_rne(a[j] - bf2f(h));
  }
  reinterpret_cast<ushort4*>(oh)[idx] = hv;
  reinterpret_cast<ushort4*>(ol)[idx] = lv;
}

// ---------- weight prep: R [K, H*F] -> outT [F, K] (sum over H), tiled LDS transpose ----------
template<int H>
__global__ void foldT_k(const float* __restrict__ R, unsigned short* __restrict__ oh,
                        unsigned short* __restrict__ ol, int K, int F, int ktiles){
  int bid = blockIdx.x;
  int f0 = (bid / ktiles) * 64, k0 = (bid % ktiles) * 64;
  __shared__ float tile[64][65];
  int t = threadIdx.x;
  {
    int tf = t & 63, tk4 = t >> 6;
    #pragma unroll
    for (int m = 0; m < 16; ++m){
      int kl = tk4 + m*4;
      float s = 0.f;
      #pragma unroll
      for (int h = 0; h < H; ++h)
        s += R[(size_t)(k0 + kl)*(H*F) + h*F + f0 + tf];
      tile[kl][tf] = s;
    }
  }
  __syncthreads();
  {
    int tk = t & 63, tf4 = t >> 6;
    #pragma unroll
    for (int m = 0; m < 16; ++m){
      int fl = tf4 + m*4;
      float s = tile[tk][fl];
      unsigned short hv = f2bf_rne(s);
      size_t o = (size_t)(f0 + fl)*K + k0 + tk;
      oh[o] = hv;
      ol[o] = f2bf_rne(s - bf2f(hv));
    }
  }
}

__global__ void bfold_k(const float* __restrict__ b, float* __restrict__ out, int H, int F){
  int f = threadIdx.x;
  if (f < F){
    float s = 0.f;
    for (int h = 0; h < H; ++h) s += b[h*F + f];
    out[f] = s;
  }
}

// ---------- split-bf16 MFMA NT GEMM (m97 structure): C[M,N] = A[M,K] * B[N,K]^T ----------
// linear LDS [128][32] per operand buffer, global_load_lds staging, 2-barrier K-loop.
// EPI: 0 = store C; 3 = C += acc, +bias, leaky(param); 4 = symmetric bitpack (upper-tri grid)
template<int EPI>
__global__ void gemm_bf(const unsigned short* __restrict__ Ah, const unsigned short* __restrict__ Al,
                        const unsigned short* __restrict__ Bh, const unsigned short* __restrict__ Bl,
                        float* __restrict__ C, u64* __restrict__ Mk,
                        int K, int lda, int ldb, int ldc, int maskld, int gridx,
                        const float* __restrict__ bias, float param){
  __shared__ unsigned short smem[4*128*32];
  unsigned short* sAh = smem;
  unsigned short* sAl = smem + 4096;
  unsigned short* sBh = smem + 8192;
  unsigned short* sBl = smem + 12288;
  const int t = threadIdx.x, lane = t & 63, w = t >> 6;
  const int wr = w >> 1, wc = w & 1, l15 = lane & 15, lg = lane >> 4;

  // XCD-aware swizzle (bijective since all our grids are %8==0)
  int nwg = gridDim.x, bid = blockIdx.x;
  int wg = ((nwg & 7) == 0) ? ((bid & 7)*(nwg >> 3) + (bid >> 3)) : bid;
  int brow, bcol;
  if (EPI == 4){
    // upper-triangular enumeration over 32x32 block grid: brow <= bcol
    int rem = wg, i = 0;
    while (rem >= 32 - i){ rem -= 32 - i; ++i; }
    brow = i; bcol = i + rem;
  } else {
    brow = wg / gridx; bcol = wg % gridx;
  }
  const int row0 = brow*128, col0 = bcol*128;

  // staging: 8 chunks of 1KB per operand buffer; wave w stages chunks 2w, 2w+1.
  const int c0 = 2*w, c1 = 2*w + 1;
  const int rsub = lane >> 2, piece = lane & 3;
  const size_t ld2a = (size_t)lda*2, ld2b = (size_t)ldb*2;
  const size_t a0 = (size_t)(row0 + 16*c0 + rsub)*ld2a + piece*16;
  const size_t a1 = (size_t)(row0 + 16*c1 + rsub)*ld2a + piece*16;
  const size_t b0 = (size_t)(col0 + 16*c0 + rsub)*ld2b + piece*16;
  const size_t b1 = (size_t)(col0 + 16*c1 + rsub)*ld2b + piece*16;
  const char* pA0h = (const char*)Ah + a0;  const char* pA1h = (const char*)Ah + a1;
  const char* pA0l = (const char*)Al + a0;  const char* pA1l = (const char*)Al + a1;
  const char* pB0h = (const char*)Bh + b0;  const char* pB1h = (const char*)Bh + b1;
  const char* pB0l = (const char*)Bl + b0;  const char* pB1l = (const char*)Bl + b1;
  char* lA0h = (char*)sAh + c0*1024;  char* lA1h = (char*)sAh + c1*1024;
  char* lA0l = (char*)sAl + c0*1024;  char* lA1l = (char*)sAl + c1*1024;
  char* lB0h = (char*)sBh + c0*1024;  char* lB1h = (char*)sBh + c1*1024;
  char* lB0l = (char*)sBl + c0*1024;  char* lB1l = (char*)sBl + c1*1024;

  f32x4 acc[4][4] = {};
  const int nk = K >> 5;
  for (int kt = 0; kt < nk; ++kt){
    __syncthreads();
    gld16(pA0h, lA0h); gld16(pA1h, lA1h);
    gld16(pA0l, lA0l); gld16(pA1l, lA1l);
    gld16(pB0h, lB0h); gld16(pB1h, lB1h);
    gld16(pB0l, lB0l); gld16(pB1l, lB1l);
    pA0h += 64; pA1h += 64; pA0l += 64; pA1l += 64;
    pB0h += 64; pB1h += 64; pB0l += 64; pB1l += 64;
    __syncthreads();
    bf16x8 fb_h[4], fb_l[4];
    #pragma unroll
    for (int j = 0; j < 4; ++j){
      int bo = (wc*64 + j*16 + l15)*32 + lg*8;
      fb_h[j] = *reinterpret_cast<const bf16x8*>(sBh + bo);
      fb_l[j] = *reinterpret_cast<const bf16x8*>(sBl + bo);
    }
    #pragma unroll
    for (int i = 0; i < 4; ++i){
      int ao = (wr*64 + i*16 + l15)*32 + lg*8;
      bf16x8 fah = *reinterpret_cast<const bf16x8*>(sAh + ao);
      bf16x8 fal = *reinterpret_cast<const bf16x8*>(sAl + ao);
      #pragma unroll
      for (int j = 0; j < 4; ++j){
        acc[i][j] = __builtin_amdgcn_mfma_f32_16x16x32_bf16(fah, fb_h[j], acc[i][j], 0, 0, 0);
        acc[i][j] = __builtin_amdgcn_mfma_f32_16x16x32_bf16(fah, fb_l[j], acc[i][j], 0, 0, 0);
        acc[i][j] = __builtin_amdgcn_mfma_f32_16x16x32_bf16(fal, fb_h[j], acc[i][j], 0, 0, 0);
      }
    }
  }

  if (EPI == 4){
    // normal bitpack: wave (wr,wc): rows wr*64.., one u64 word (cols wc*64..+63) per row
    #pragma unroll
    for (int i = 0; i < 4; ++i){
      #pragma unroll
      for (int r = 0; r < 4; ++r){
        u64 bits = 0ull;
        #pragma unroll
        for (int j = 0; j < 4; ++j)
          if (acc[i][j][r] > param) bits |= 1ull << (j*16 + l15);
        #pragma unroll
        for (int m = 1; m <= 8; m <<= 1) bits |= __shfl_xor(bits, m);
        if (l15 == 0){
          int gr = row0 + wr*64 + i*16 + lg*4 + r;
          Mk[(size_t)gr*maskld + (col0 >> 6) + wc] = bits;
        }
      }
    }
    // transposed bitpack for the mirror block (off-diagonal only)
    if (row0 != col0){
      #pragma unroll
      for (int j = 0; j < 4; ++j){
        u64 tb = 0ull;
        #pragma unroll
        for (int i = 0; i < 4; ++i)
          #pragma unroll
          for (int r = 0; r < 4; ++r)
            if (acc[i][j][r] > param) tb |= 1ull << (i*16 + lg*4 + r);
        tb |= __shfl_xor(tb, 16);
        tb |= __shfl_xor(tb, 32);
        if (lg == 0){
          int gc = col0 + wc*64 + j*16 + l15;
          Mk[(size_t)gc*maskld + (row0 >> 6) + wr] = tb;
        }
      }
    }
  } else {
    #pragma unroll
    for (int i = 0; i < 4; ++i){
      int gr = row0 + wr*64 + i*16 + lg*4;
      #pragma unroll
      for (int j = 0; j < 4; ++j){
        int gc = col0 + wc*64 + j*16 + l15;
        #pragma unroll
        for (int r = 0; r < 4; ++r){
          float v = acc[i][j][r];
          size_t o = (size_t)(gr + r)*ldc + gc;
          if (EPI == 3){
            v += C[o] + bias[gc];
            v = v > 0.f ? v : param*v;
          }
          C[o] = v;
        }
      }
    }
  }
}

// ---------- el / er per node ----------
template<int H>
__global__ void el_er_k(const float* __restrict__ feat, int ldf,
                        const float* __restrict__ al, const float* __restrict__ ar,
                        float* __restrict__ el, float* __restrict__ er){
  int n = blockIdx.x, t = threadIdx.x;
  __shared__ float red[8];
  #pragma unroll
  for (int h = 0; h < H; ++h){
    float v = feat[(size_t)n*ldf + h*HD_ + t];
    float a = v * al[h*HD_ + t];
    float b = v * ar[h*HD_ + t];
    #pragma unroll
    for (int o = 32; o > 0; o >>= 1){ a += __shfl_down(a, o); b += __shfl_down(b, o); }
    if ((t & 63) == 0){ red[t >> 6] = a; red[4 + (t >> 6)] = b; }
    __syncthreads();
    if (t == 0){
      el[n*H + h] = red[0] + red[1] + red[2] + red[3];
      er[n*H + h] = red[4] + red[5] + red[6] + red[7];
    }
    __syncthreads();
  }
}

// ---------- softmax stats (max, denom) per dst ----------
template<int H>
__global__ void stats_k(const u64* __restrict__ Mk,
                        const float* __restrict__ el, const float* __restrict__ er,
                        float* __restrict__ mo, float* __restrict__ lo){
  int d = blockIdx.x, t = threadIdx.x;
  float erd[H], mx[H];
  #pragma unroll
  for (int h = 0; h < H; ++h){ erd[h] = er[d*H + h]; mx[h] = -1e30f; }
  for (int s = t; s < NNODE; s += 256){
    u64 w = Mk[(size_t)d*64 + (s >> 6)];
    if ((w >> (s & 63)) & 1ull){
      #pragma unroll
      for (int h = 0; h < H; ++h){
        float e = erd[h] + el[s*H + h];
        e = e > 0.f ? e : 0.2f*e;
        mx[h] = fmaxf(mx[h], e);
      }
    }
  }
  __shared__ float red[H*4];
  __shared__ float mfin[H];
  #pragma unroll
  for (int h = 0; h < H; ++h){
    float v = mx[h];
    #pragma unroll
    for (int o = 32; o > 0; o >>= 1) v = fmaxf(v, __shfl_down(v, o));
    if ((t & 63) == 0) red[h*4 + (t >> 6)] = v;
  }
  __syncthreads();
  if (t == 0){
    #pragma unroll
    for (int h = 0; h < H; ++h)
      mfin[h] = fmaxf(fmaxf(red[h*4+0], red[h*4+1]), fmaxf(red[h*4+2], red[h*4+3]));
  }
  __syncthreads();
  float sm[H];
  #pragma unroll
  for (int h = 0; h < H; ++h) sm[h] = 0.f;
  for (int s = t; s < NNODE; s += 256){
    u64 w = Mk[(size_t)d*64 + (s >> 6)];
    if ((w >> (s & 63)) & 1ull){
      #pragma unroll
      for (int h = 0; h < H; ++h){
        float e = erd[h] + el[s*H + h];
        e = e > 0.f ? e : 0.2f*e;
        sm[h] += __expf(e - mfin[h]);
      }
    }
  }
  __syncthreads();
  #pragma unroll
  for (int h = 0; h < H; ++h){
    float v = sm[h];
    #pragma unroll
    for (int o = 32; o > 0; o >>= 1) v += __shfl_down(v, o);
    if ((t & 63) == 0) red[h*4 + (t >> 6)] = v;
  }
  __syncthreads();
  if (t == 0){
    #pragma unroll
    for (int h = 0; h < H; ++h){
      mo[d*H + h] = mfin[h];
      lo[d*H + h] = red[h*4+0] + red[h*4+1] + red[h*4+2] + red[h*4+3];
    }
  }
}

// ---------- aggregation ----------
template<int H, bool RELU>
__global__ void agg_k(const float* __restrict__ feat, int ldf,
                      const u64* __restrict__ Mk,
                      const float* __restrict__ el, const float* __restrict__ er,
                      const float* __restrict__ mo, const float* __restrict__ lo,
                      const float* __restrict__ res, int ldres,
                      const float* __restrict__ bias,
                      float* __restrict__ out){
  int d = blockIdx.x, t = threadIdx.x;
  float erd[H], md[H], li[H], acc[H];
  #pragma unroll
  for (int h = 0; h < H; ++h){
    erd[h] = er[d*H + h];
    md[h]  = mo[d*H + h];
    li[h]  = 1.f / lo[d*H + h];
    acc[h] = 0.f;
  }
  for (int w = 0; w < 64; ++w){
    u64 bits = Mk[(size_t)d*64 + w];
    while (bits){
      int b = __builtin_ctzll(bits);
      bits &= bits - 1ull;
      int s = w*64 + b;
      #pragma unroll
      for (int h = 0; h < H; ++h){
        float e = erd[h] + el[s*H + h];
        e = e > 0.f ? e : 0.2f*e;
        float wt = __expf(e - md[h]) * li[h];
        acc[h] += wt * feat[(size_t)s*ldf + h*HD_ + t];
      }
    }
  }
  float v = 0.f;
  #pragma unroll
  for (int h = 0; h < H; ++h) v += acc[h];
  v += res[(size_t)d*ldres + t];
  v += bias[t];
  if (RELU) v = fmaxf(v, 0.f);
  out[(size_t)d*HD_ + t] = v;
}

// ---------- classifier head ----------
__global__ void head_k(const float* __restrict__ A, int K, const float* __restrict__ W,
                       const float* __restrict__ b, float* __restrict__ out){
  int row = blockIdx.x, t = threadIdx.x;
  float p[NC_];
  #pragma unroll
  for (int j = 0; j < NC_; ++j) p[j] = 0.f;
  for (int k = t; k < K; k += 256){
    float a = A[(size_t)row*K + k];
    #pragma unroll
    for (int j = 0; j < NC_; ++j) p[j] += a * W[k*NC_ + j];
  }
  #pragma unroll
  for (int j = 0; j < NC_; ++j){
    #pragma unroll
    for (int o = 32; o > 0; o >>= 1) p[j] += __shfl_down(p[j], o);
  }
  __shared__ float red[4][NC_];
  if ((t & 63) == 0){
    #pragma unroll
    for (int j = 0; j < NC_; ++j) red[t >> 6][j] = p[j];
  }
  __syncthreads();
  if (t < NC_)
    out[(size_t)row*NC_ + t] = red[0][t] + red[1][t] + red[2][t] + red[3][t] + b[t];
}

// ---------- launch ----------
extern "C" void kernel_launch(void* const* d_in, const int* in_sizes, int n_in,
                              void* d_out, int out_size, void* d_ws, size_t ws_size,
                              hipStream_t stream){
  const float* x   = (const float*)d_in[0];
  const float* W0  = (const float*)d_in[1];
  const float* al0 = (const float*)d_in[2];
  const float* ar0 = (const float*)d_in[3];
  const float* b0  = (const float*)d_in[4];
  const float* R0  = (const float*)d_in[5];
  const float* W1  = (const float*)d_in[6];
  const float* al1 = (const float*)d_in[7];
  const float* ar1 = (const float*)d_in[8];
  const float* b1  = (const float*)d_in[9];
  const float* R1  = (const float*)d_in[10];
  const float* W2  = (const float*)d_in[11];
  const float* al2 = (const float*)d_in[12];
  const float* ar2 = (const float*)d_in[13];
  const float* b2  = (const float*)d_in[14];
  const float* Wl1 = (const float*)d_in[15];
  const float* bl1 = (const float*)d_in[16];
  const float* Wc1 = (const float*)d_in[17];
  const float* bc1 = (const float*)d_in[18];
  const float* Wc2 = (const float*)d_in[19];
  const float* bc2 = (const float*)d_in[20];
  (void)in_sizes; (void)n_in; (void)out_size; (void)ws_size;

  char* ws = (char*)d_ws;
  size_t off = 0;
  auto alloc = [&](size_t bytes)->char*{
    char* p = ws + off; off += (bytes + 255) & ~(size_t)255; return p;
  };
  typedef unsigned short us;
  u64* MASK = (u64*)alloc((size_t)NNODE*64*8);
  us* W0h = (us*)alloc((size_t)1280*2048*2);  us* W0l = (us*)alloc((size_t)1280*2048*2);
  us* W1h = (us*)alloc((size_t)1280*256*2);   us* W1l = (us*)alloc((size_t)1280*256*2);
  us* W2h = (us*)alloc((size_t)256*256*2);    us* W2l = (us*)alloc((size_t)256*256*2);
  us* WLh = (us*)alloc((size_t)1024*2304*2);  us* WLl = (us*)alloc((size_t)1024*2304*2);
  float* BF0 = (float*)alloc(256*4);
  float* BF1 = (float*)alloc(256*4);
  float* EL  = (float*)alloc((size_t)NNODE*4*4);
  float* ER  = (float*)alloc((size_t)NNODE*4*4);
  float* MO  = (float*)alloc((size_t)NNODE*4*4);
  float* LO  = (float*)alloc((size_t)NNODE*4*4);
  us* XNh = (us*)alloc((size_t)NNODE*FIND*2);  // reused as FT (fp32, 21MB) after Gram
  us* XNl = (us*)alloc((size_t)NNODE*FIND*2);
  us* Xh  = (us*)alloc((size_t)NNODE*FIND*2);
  us* Xl  = (us*)alloc((size_t)NNODE*FIND*2);
  float* H1 = (float*)alloc((size_t)NNODE*HD_*4);
  float* H2 = (float*)alloc((size_t)NNODE*HD_*4);
  float* H3 = (float*)alloc((size_t)NNODE*HD_*4);
  us* H1h = (us*)alloc((size_t)NNODE*HD_*2);  us* H1l = (us*)alloc((size_t)NNODE*HD_*2);
  us* H2h = (us*)alloc((size_t)NNODE*HD_*2);  us* H2l = (us*)alloc((size_t)NNODE*HD_*2);
  us* H3h = (us*)alloc((size_t)NNODE*HD_*2);  us* H3l = (us*)alloc((size_t)NNODE*HD_*2);
  float* Z1 = (float*)alloc((size_t)NNODE*1024*4);

  float* FT = (float*)XNh;
  float* out1 = (float*)d_out;
  float* out2 = out1 + (size_t)NNODE*NC_;

  // ---- weight & input prep (tiled transposes, coalesced) ----
  foldT_k<1><<<512, 256, 0, stream>>>(W0, W0h, W0l, 2048, 1024, 32);
  foldT_k<4><<<128, 256, 0, stream>>>(R0, W0h + (size_t)1024*2048, W0l + (size_t)1024*2048, 2048, 256, 32);
  foldT_k<1><<< 64, 256, 0, stream>>>(W1, W1h, W1l, 256, 1024, 4);
  foldT_k<4><<< 16, 256, 0, stream>>>(R1, W1h + (size_t)1024*256, W1l + (size_t)1024*256, 256, 256, 4);
  foldT_k<1><<< 16, 256, 0, stream>>>(W2, W2h, W2l, 256, 256, 4);
  foldT_k<1><<<576, 256, 0, stream>>>(Wl1, WLh, WLl, 2304, 1024, 36);
  bfold_k<<<1, 256, 0, stream>>>(b0, BF0, 4, 256);
  bfold_k<<<1, 256, 0, stream>>>(b1, BF1, 4, 256);
  f2bf_k<<<(NNODE*FIND/4+255)/256, 256, 0, stream>>>(x, Xh, Xl, NNODE*FIND/4);
  rownorm_bf<<<NNODE, 256, 0, stream>>>(x, XNh, XNl);

  // ---- graph construction: symmetric Gram, upper-tri 528 blocks ----
  gemm_bf<4><<<528, 256, 0, stream>>>(XNh, XNl, XNh, XNl, nullptr, MASK,
      FIND, FIND, FIND, 0, 64, 1, nullptr, THRESH_);

  // ---- GAT layer 0: [4096 x 1280] = x @ [W0|sumR0]^T ----
  gemm_bf<0><<<320, 256, 0, stream>>>(Xh, Xl, W0h, W0l, FT, nullptr,
      FIND, FIND, FIND, 1280, 0, 10, nullptr, 0.f);
  el_er_k<4><<<NNODE, 256, 0, stream>>>(FT, 1280, al0, ar0, EL, ER);
  stats_k<4><<<NNODE, 256, 0, stream>>>(MASK, EL, ER, MO, LO);
  agg_k<4,true><<<NNODE, 256, 0, stream>>>(FT, 1280, MASK, EL, ER, MO, LO,
      FT + 1024, 1280, BF0, H1);

  // ---- GAT layer 1 ----
  f2bf_k<<<(NNODE*HD_/4+255)/256, 256, 0, stream>>>(H1, H1h, H1l, NNODE*HD_/4);
  gemm_bf<0><<<320, 256, 0, stream>>>(H1h, H1l, W1h, W1l, FT, nullptr,
      256, 256, 256, 1280, 0, 10, nullptr, 0.f);
  el_er_k<4><<<NNODE, 256, 0, stream>>>(FT, 1280, al1, ar1, EL, ER);
  stats_k<4><<<NNODE, 256, 0, stream>>>(MASK, EL, ER, MO, LO);
  agg_k<4,true><<<NNODE, 256, 0, stream>>>(FT, 1280, MASK, EL, ER, MO, LO,
      FT + 1024, 1280, BF1, H2);

  // ---- GAT layer 2 (1 head, identity residual, no relu) ----
  f2bf_k<<<(NNODE*HD_/4+255)/256, 256, 0, stream>>>(H2, H2h, H2l, NNODE*HD_/4);
  gemm_bf<0><<<64, 256, 0, stream>>>(H2h, H2l, W2h, W2l, FT, nullptr,
      256, 256, 256, 256, 0, 2, nullptr, 0.f);
  el_er_k<1><<<NNODE, 256, 0, stream>>>(FT, 256, al2, ar2, EL, ER);
  stats_k<1><<<NNODE, 256, 0, stream>>>(MASK, EL, ER, MO, LO);
  agg_k<1,false><<<NNODE, 256, 0, stream>>>(FT, 256, MASK, EL, ER, MO, LO,
      H2, 256, b2, H3);

  // ---- MLP: Z1 = leaky([x,h3] @ Wl1 + bl1) via K-split accumulate ----
  f2bf_k<<<(NNODE*HD_/4+255)/256, 256, 0, stream>>>(H3, H3h, H3l, NNODE*HD_/4);
  gemm_bf<0><<<256, 256, 0, stream>>>(Xh, Xl, WLh, WLl, Z1, nullptr,
      FIND, FIND, 2304, 1024, 0, 8, nullptr, 0.f);
  gemm_bf<3><<<256, 256, 0, stream>>>(H3h, H3l, WLh + 2048, WLl + 2048, Z1, nullptr,
      256, 256, 2304, 1024, 0, 8, bl1, 0.01f);

  head_k<<<NNODE, 256, 0, stream>>>(Z1, 1024, Wc1, bc1, out1);
  head_k<<<NNODE, 256, 0, stream>>>(x, FIND, Wc2, bc2, out2);
}

// Round 5
// 730.161 us; speedup vs baseline: 2.7829x; 1.1320x over previous
//
#include <hip/hip_runtime.h>
#include <cstdint>
#include <cstddef>

#define NNODE 4096
#define FIND  2048
#define HD_   256
#define NC_   10
#define THRESH_ 0.05f

typedef unsigned long long u64;
typedef __attribute__((ext_vector_type(8))) short bf16x8;
typedef __attribute__((ext_vector_type(4))) float f32x4;

// ---------- bf16 split helpers ----------
__device__ inline unsigned short f2bf_rne(float f){
  unsigned u = __builtin_bit_cast(unsigned, f);
  unsigned r = u + 0x7FFFu + ((u >> 16) & 1u);
  return (unsigned short)(r >> 16);
}
__device__ inline float bf2f(unsigned short h){
  unsigned u = ((unsigned)h) << 16;
  return __builtin_bit_cast(float, u);
}

// async global->LDS, 16B per lane; lds dest is wave-uniform base (+lane*16 by HW)
__device__ __forceinline__ void gld16(const void* g, void* l){
  __builtin_amdgcn_global_load_lds(
      (const __attribute__((address_space(1))) unsigned int*)g,
      (__attribute__((address_space(3))) unsigned int*)l, 16, 0, 0);
}

// ---------- row normalize -> hi/lo bf16 ----------
__global__ void rownorm_bf(const float* __restrict__ x,
                           unsigned short* __restrict__ oh, unsigned short* __restrict__ ol){
  int row = blockIdx.x; int t = threadIdx.x;
  const float4* xr = reinterpret_cast<const float4*>(x + (size_t)row*FIND);
  float s = 0.f;
  #pragma unroll
  for (int i = 0; i < FIND/4/256; ++i){
    float4 v = xr[t + i*256];
    s += v.x*v.x + v.y*v.y + v.z*v.z + v.w*v.w;
  }
  #pragma unroll
  for (int o = 32; o > 0; o >>= 1) s += __shfl_down(s, o);
  __shared__ float red[4];
  __shared__ float invn;
  if ((t & 63) == 0) red[t >> 6] = s;
  __syncthreads();
  if (t == 0) invn = rsqrtf(red[0] + red[1] + red[2] + red[3]);
  __syncthreads();
  float inv = invn;
  #pragma unroll
  for (int i = 0; i < FIND/4/256; ++i){
    float4 v = xr[t + i*256];
    float a[4] = {v.x*inv, v.y*inv, v.z*inv, v.w*inv};
    ushort4 hv, lv;
    unsigned short* hp = &hv.x; unsigned short* lp = &lv.x;
    #pragma unroll
    for (int j = 0; j < 4; ++j){
      unsigned short h = f2bf_rne(a[j]);
      hp[j] = h; lp[j] = f2bf_rne(a[j] - bf2f(h));
    }
    size_t off = (size_t)row*FIND + (t + i*256)*4;
    *reinterpret_cast<ushort4*>(oh + off) = hv;
    *reinterpret_cast<ushort4*>(ol + off) = lv;
  }
}

// ---------- fp32 -> hi/lo bf16 (vectorized) ----------
__global__ void f2bf_k(const float* __restrict__ in, unsigned short* __restrict__ oh,
                       unsigned short* __restrict__ ol, int n4){
  int idx = blockIdx.x*256 + threadIdx.x;
  if (idx >= n4) return;
  float4 v = reinterpret_cast<const float4*>(in)[idx];
  float a[4] = {v.x, v.y, v.z, v.w};
  ushort4 hv, lv;
  unsigned short* hp = &hv.x; unsigned short* lp = &lv.x;
  #pragma unroll
  for (int j = 0; j < 4; ++j){
    unsigned short h = f2bf_rne(a[j]);
    hp[j] = h; lp[j] = f2bf_rne(a[j] - bf2f(h));
  }
  reinterpret_cast<ushort4*>(oh)[idx] = hv;
  reinterpret_cast<ushort4*>(ol)[idx] = lv;
}

// ---------- weight prep: R [K, H*F] -> outT [F, K] (sum over H), tiled LDS transpose ----------
template<int H>
__global__ void foldT_k(const float* __restrict__ R, unsigned short* __restrict__ oh,
                        unsigned short* __restrict__ ol, int K, int F, int ktiles){
  int bid = blockIdx.x;
  int f0 = (bid / ktiles) * 64, k0 = (bid % ktiles) * 64;
  __shared__ float tile[64][65];
  int t = threadIdx.x;
  {
    int tf = t & 63, tk4 = t >> 6;
    #pragma unroll
    for (int m = 0; m < 16; ++m){
      int kl = tk4 + m*4;
      float s = 0.f;
      #pragma unroll
      for (int h = 0; h < H; ++h)
        s += R[(size_t)(k0 + kl)*(H*F) + h*F + f0 + tf];
      tile[kl][tf] = s;
    }
  }
  __syncthreads();
  {
    int tk = t & 63, tf4 = t >> 6;
    #pragma unroll
    for (int m = 0; m < 16; ++m){
      int fl = tf4 + m*4;
      float s = tile[tk][fl];
      unsigned short hv = f2bf_rne(s);
      size_t o = (size_t)(f0 + fl)*K + k0 + tk;
      oh[o] = hv;
      ol[o] = f2bf_rne(s - bf2f(hv));
    }
  }
}

__global__ void bfold_k(const float* __restrict__ b, float* __restrict__ out, int H, int F){
  int f = threadIdx.x;
  if (f < F){
    float s = 0.f;
    for (int h = 0; h < H; ++h) s += b[h*F + f];
    out[f] = s;
  }
}

// ---------- MEGA GEMM: Gram(upper-tri, bitpack) + GAT0 feat + MLP x-part in one grid ----------
// All roles: K=2048, split-bf16 3-term, m97-style staging. Grid = 528 + 320 + 256 = 1104.
__global__ void mega_gemm(const unsigned short* __restrict__ XNh, const unsigned short* __restrict__ XNl,
                          const unsigned short* __restrict__ Xh,  const unsigned short* __restrict__ Xl,
                          const unsigned short* __restrict__ W0h, const unsigned short* __restrict__ W0l,
                          const unsigned short* __restrict__ WLh, const unsigned short* __restrict__ WLl,
                          float* __restrict__ FT, float* __restrict__ Z1, u64* __restrict__ Mk){
  __shared__ unsigned short smem[4*128*32];
  unsigned short* sAh = smem;
  unsigned short* sAl = smem + 4096;
  unsigned short* sBh = smem + 8192;
  unsigned short* sBl = smem + 12288;
  const int t = threadIdx.x, lane = t & 63, w = t >> 6;
  const int wr = w >> 1, wc = w & 1, l15 = lane & 15, lg = lane >> 4;

  int nwg = gridDim.x, bid = blockIdx.x;
  int wg = (bid & 7)*(nwg >> 3) + (bid >> 3);   // 1104 % 8 == 0 -> bijective

  int role, brow, bcol;
  const unsigned short *Ah, *Al, *Bh, *Bl;
  float* C = nullptr; int ldc = 0; size_t ldb;
  if (wg < 528){
    role = 0;
    int rem = wg, i = 0;
    while (rem >= 32 - i){ rem -= 32 - i; ++i; }
    brow = i; bcol = i + rem;
    Ah = XNh; Al = XNl; Bh = XNh; Bl = XNl; ldb = FIND;
  } else if (wg < 848){
    role = 1;
    int l = wg - 528; brow = l / 10; bcol = l % 10;
    Ah = Xh; Al = Xl; Bh = W0h; Bl = W0l; ldb = FIND;
    C = FT; ldc = 1280;
  } else {
    role = 2;
    int l = wg - 848; brow = l >> 3; bcol = l & 7;
    Ah = Xh; Al = Xl; Bh = WLh; Bl = WLl; ldb = 2304;
    C = Z1; ldc = 1024;
  }
  const int row0 = brow*128, col0 = bcol*128;

  // staging: 8 chunks of 1KB per operand buffer; wave w stages chunks 2w, 2w+1.
  const int c0 = 2*w, c1 = 2*w + 1;
  const int rsub = lane >> 2, piece = lane & 3;
  const size_t ld2a = (size_t)FIND*2, ld2b = ldb*2;
  const size_t a0 = (size_t)(row0 + 16*c0 + rsub)*ld2a + piece*16;
  const size_t a1 = (size_t)(row0 + 16*c1 + rsub)*ld2a + piece*16;
  const size_t b0 = (size_t)(col0 + 16*c0 + rsub)*ld2b + piece*16;
  const size_t b1 = (size_t)(col0 + 16*c1 + rsub)*ld2b + piece*16;
  const char* pA0h = (const char*)Ah + a0;  const char* pA1h = (const char*)Ah + a1;
  const char* pA0l = (const char*)Al + a0;  const char* pA1l = (const char*)Al + a1;
  const char* pB0h = (const char*)Bh + b0;  const char* pB1h = (const char*)Bh + b1;
  const char* pB0l = (const char*)Bl + b0;  const char* pB1l = (const char*)Bl + b1;
  char* lA0h = (char*)sAh + c0*1024;  char* lA1h = (char*)sAh + c1*1024;
  char* lA0l = (char*)sAl + c0*1024;  char* lA1l = (char*)sAl + c1*1024;
  char* lB0h = (char*)sBh + c0*1024;  char* lB1h = (char*)sBh + c1*1024;
  char* lB0l = (char*)sBl + c0*1024;  char* lB1l = (char*)sBl + c1*1024;

  f32x4 acc[4][4] = {};
  for (int kt = 0; kt < 64; ++kt){
    __syncthreads();
    gld16(pA0h, lA0h); gld16(pA1h, lA1h);
    gld16(pA0l, lA0l); gld16(pA1l, lA1l);
    gld16(pB0h, lB0h); gld16(pB1h, lB1h);
    gld16(pB0l, lB0l); gld16(pB1l, lB1l);
    pA0h += 64; pA1h += 64; pA0l += 64; pA1l += 64;
    pB0h += 64; pB1h += 64; pB0l += 64; pB1l += 64;
    __syncthreads();
    bf16x8 fb_h[4], fb_l[4];
    #pragma unroll
    for (int j = 0; j < 4; ++j){
      int bo = (wc*64 + j*16 + l15)*32 + lg*8;
      fb_h[j] = *reinterpret_cast<const bf16x8*>(sBh + bo);
      fb_l[j] = *reinterpret_cast<const bf16x8*>(sBl + bo);
    }
    #pragma unroll
    for (int i = 0; i < 4; ++i){
      int ao = (wr*64 + i*16 + l15)*32 + lg*8;
      bf16x8 fah = *reinterpret_cast<const bf16x8*>(sAh + ao);
      bf16x8 fal = *reinterpret_cast<const bf16x8*>(sAl + ao);
      #pragma unroll
      for (int j = 0; j < 4; ++j){
        acc[i][j] = __builtin_amdgcn_mfma_f32_16x16x32_bf16(fah, fb_h[j], acc[i][j], 0, 0, 0);
        acc[i][j] = __builtin_amdgcn_mfma_f32_16x16x32_bf16(fah, fb_l[j], acc[i][j], 0, 0, 0);
        acc[i][j] = __builtin_amdgcn_mfma_f32_16x16x32_bf16(fal, fb_h[j], acc[i][j], 0, 0, 0);
      }
    }
  }

  if (role == 0){
    // normal bitpack: wave (wr,wc): rows wr*64.., one u64 word (cols wc*64..+63) per row
    #pragma unroll
    for (int i = 0; i < 4; ++i){
      #pragma unroll
      for (int r = 0; r < 4; ++r){
        u64 bits = 0ull;
        #pragma unroll
        for (int j = 0; j < 4; ++j)
          if (acc[i][j][r] > THRESH_) bits |= 1ull << (j*16 + l15);
        #pragma unroll
        for (int m = 1; m <= 8; m <<= 1) bits |= __shfl_xor(bits, m);
        if (l15 == 0){
          int gr = row0 + wr*64 + i*16 + lg*4 + r;
          Mk[(size_t)gr*64 + (col0 >> 6) + wc] = bits;
        }
      }
    }
    // transposed bitpack for the mirror block (off-diagonal only)
    if (row0 != col0){
      #pragma unroll
      for (int j = 0; j < 4; ++j){
        u64 tb = 0ull;
        #pragma unroll
        for (int i = 0; i < 4; ++i)
          #pragma unroll
          for (int r = 0; r < 4; ++r)
            if (acc[i][j][r] > THRESH_) tb |= 1ull << (i*16 + lg*4 + r);
        tb |= __shfl_xor(tb, 16);
        tb |= __shfl_xor(tb, 32);
        if (lg == 0){
          int gc = col0 + wc*64 + j*16 + l15;
          Mk[(size_t)gc*64 + (row0 >> 6) + wr] = tb;
        }
      }
    }
  } else {
    #pragma unroll
    for (int i = 0; i < 4; ++i){
      int gr = row0 + wr*64 + i*16 + lg*4;
      #pragma unroll
      for (int j = 0; j < 4; ++j){
        int gc = col0 + wc*64 + j*16 + l15;
        #pragma unroll
        for (int r = 0; r < 4; ++r)
          C[(size_t)(gr + r)*ldc + gc] = acc[i][j][r];
      }
    }
  }
}

// ---------- split-bf16 MFMA NT GEMM (m97 structure) for short-K layers ----------
// EPI: 0 = store C; 3 = C += acc, +bias, leaky(param)
template<int EPI>
__global__ void gemm_bf(const unsigned short* __restrict__ Ah, const unsigned short* __restrict__ Al,
                        const unsigned short* __restrict__ Bh, const unsigned short* __restrict__ Bl,
                        float* __restrict__ C,
                        int K, int lda, int ldb, int ldc, int gridx,
                        const float* __restrict__ bias, float param){
  __shared__ unsigned short smem[4*128*32];
  unsigned short* sAh = smem;
  unsigned short* sAl = smem + 4096;
  unsigned short* sBh = smem + 8192;
  unsigned short* sBl = smem + 12288;
  const int t = threadIdx.x, lane = t & 63, w = t >> 6;
  const int wr = w >> 1, wc = w & 1, l15 = lane & 15, lg = lane >> 4;

  int nwg = gridDim.x, bid = blockIdx.x;
  int wg = ((nwg & 7) == 0) ? ((bid & 7)*(nwg >> 3) + (bid >> 3)) : bid;
  int brow = wg / gridx, bcol = wg % gridx;
  const int row0 = brow*128, col0 = bcol*128;

  const int c0 = 2*w, c1 = 2*w + 1;
  const int rsub = lane >> 2, piece = lane & 3;
  const size_t ld2a = (size_t)lda*2, ld2b = (size_t)ldb*2;
  const size_t a0 = (size_t)(row0 + 16*c0 + rsub)*ld2a + piece*16;
  const size_t a1 = (size_t)(row0 + 16*c1 + rsub)*ld2a + piece*16;
  const size_t b0 = (size_t)(col0 + 16*c0 + rsub)*ld2b + piece*16;
  const size_t b1 = (size_t)(col0 + 16*c1 + rsub)*ld2b + piece*16;
  const char* pA0h = (const char*)Ah + a0;  const char* pA1h = (const char*)Ah + a1;
  const char* pA0l = (const char*)Al + a0;  const char* pA1l = (const char*)Al + a1;
  const char* pB0h = (const char*)Bh + b0;  const char* pB1h = (const char*)Bh + b1;
  const char* pB0l = (const char*)Bl + b0;  const char* pB1l = (const char*)Bl + b1;
  char* lA0h = (char*)sAh + c0*1024;  char* lA1h = (char*)sAh + c1*1024;
  char* lA0l = (char*)sAl + c0*1024;  char* lA1l = (char*)sAl + c1*1024;
  char* lB0h = (char*)sBh + c0*1024;  char* lB1h = (char*)sBh + c1*1024;
  char* lB0l = (char*)sBl + c0*1024;  char* lB1l = (char*)sBl + c1*1024;

  f32x4 acc[4][4] = {};
  const int nk = K >> 5;
  for (int kt = 0; kt < nk; ++kt){
    __syncthreads();
    gld16(pA0h, lA0h); gld16(pA1h, lA1h);
    gld16(pA0l, lA0l); gld16(pA1l, lA1l);
    gld16(pB0h, lB0h); gld16(pB1h, lB1h);
    gld16(pB0l, lB0l); gld16(pB1l, lB1l);
    pA0h += 64; pA1h += 64; pA0l += 64; pA1l += 64;
    pB0h += 64; pB1h += 64; pB0l += 64; pB1l += 64;
    __syncthreads();
    bf16x8 fb_h[4], fb_l[4];
    #pragma unroll
    for (int j = 0; j < 4; ++j){
      int bo = (wc*64 + j*16 + l15)*32 + lg*8;
      fb_h[j] = *reinterpret_cast<const bf16x8*>(sBh + bo);
      fb_l[j] = *reinterpret_cast<const bf16x8*>(sBl + bo);
    }
    #pragma unroll
    for (int i = 0; i < 4; ++i){
      int ao = (wr*64 + i*16 + l15)*32 + lg*8;
      bf16x8 fah = *reinterpret_cast<const bf16x8*>(sAh + ao);
      bf16x8 fal = *reinterpret_cast<const bf16x8*>(sAl + ao);
      #pragma unroll
      for (int j = 0; j < 4; ++j){
        acc[i][j] = __builtin_amdgcn_mfma_f32_16x16x32_bf16(fah, fb_h[j], acc[i][j], 0, 0, 0);
        acc[i][j] = __builtin_amdgcn_mfma_f32_16x16x32_bf16(fah, fb_l[j], acc[i][j], 0, 0, 0);
        acc[i][j] = __builtin_amdgcn_mfma_f32_16x16x32_bf16(fal, fb_h[j], acc[i][j], 0, 0, 0);
      }
    }
  }

  #pragma unroll
  for (int i = 0; i < 4; ++i){
    int gr = row0 + wr*64 + i*16 + lg*4;
    #pragma unroll
    for (int j = 0; j < 4; ++j){
      int gc = col0 + wc*64 + j*16 + l15;
      #pragma unroll
      for (int r = 0; r < 4; ++r){
        float v = acc[i][j][r];
        size_t o = (size_t)(gr + r)*ldc + gc;
        if (EPI == 3){
          v += C[o] + bias[gc];
          v = v > 0.f ? v : param*v;
        }
        C[o] = v;
      }
    }
  }
}

// ---------- el / er per node ----------
template<int H>
__global__ void el_er_k(const float* __restrict__ feat, int ldf,
                        const float* __restrict__ al, const float* __restrict__ ar,
                        float* __restrict__ el, float* __restrict__ er){
  int n = blockIdx.x, t = threadIdx.x;
  __shared__ float red[8];
  #pragma unroll
  for (int h = 0; h < H; ++h){
    float v = feat[(size_t)n*ldf + h*HD_ + t];
    float a = v * al[h*HD_ + t];
    float b = v * ar[h*HD_ + t];
    #pragma unroll
    for (int o = 32; o > 0; o >>= 1){ a += __shfl_down(a, o); b += __shfl_down(b, o); }
    if ((t & 63) == 0){ red[t >> 6] = a; red[4 + (t >> 6)] = b; }
    __syncthreads();
    if (t == 0){
      el[n*H + h] = red[0] + red[1] + red[2] + red[3];
      er[n*H + h] = red[4] + red[5] + red[6] + red[7];
    }
    __syncthreads();
  }
}

// ---------- fused softmax stats + aggregation per dst ----------
template<int H, bool RELU>
__global__ void sagg_k(const float* __restrict__ feat, int ldf,
                       const u64* __restrict__ Mk,
                       const float* __restrict__ el, const float* __restrict__ er,
                       const float* __restrict__ res, int ldres,
                       const float* __restrict__ bias,
                       float* __restrict__ out){
  int d = blockIdx.x, t = threadIdx.x;
  float erd[H];
  #pragma unroll
  for (int h = 0; h < H; ++h) erd[h] = er[d*H + h];
  __shared__ float red[H*4];
  __shared__ float mfin[H];
  __shared__ float lsh[H];
  // pass 1: max
  float mx[H];
  #pragma unroll
  for (int h = 0; h < H; ++h) mx[h] = -1e30f;
  for (int s = t; s < NNODE; s += 256){
    u64 wd = Mk[(size_t)d*64 + (s >> 6)];
    if ((wd >> (s & 63)) & 1ull){
      #pragma unroll
      for (int h = 0; h < H; ++h){
        float e = erd[h] + el[s*H + h];
        e = e > 0.f ? e : 0.2f*e;
        mx[h] = fmaxf(mx[h], e);
      }
    }
  }
  #pragma unroll
  for (int h = 0; h < H; ++h){
    float v = mx[h];
    #pragma unroll
    for (int o = 32; o > 0; o >>= 1) v = fmaxf(v, __shfl_down(v, o));
    if ((t & 63) == 0) red[h*4 + (t >> 6)] = v;
  }
  __syncthreads();
  if (t == 0){
    #pragma unroll
    for (int h = 0; h < H; ++h)
      mfin[h] = fmaxf(fmaxf(red[h*4+0], red[h*4+1]), fmaxf(red[h*4+2], red[h*4+3]));
  }
  __syncthreads();
  // pass 2: denom
  float sm[H];
  #pragma unroll
  for (int h = 0; h < H; ++h) sm[h] = 0.f;
  for (int s = t; s < NNODE; s += 256){
    u64 wd = Mk[(size_t)d*64 + (s >> 6)];
    if ((wd >> (s & 63)) & 1ull){
      #pragma unroll
      for (int h = 0; h < H; ++h){
        float e = erd[h] + el[s*H + h];
        e = e > 0.f ? e : 0.2f*e;
        sm[h] += __expf(e - mfin[h]);
      }
    }
  }
  __syncthreads();
  #pragma unroll
  for (int h = 0; h < H; ++h){
    float v = sm[h];
    #pragma unroll
    for (int o = 32; o > 0; o >>= 1) v += __shfl_down(v, o);
    if ((t & 63) == 0) red[h*4 + (t >> 6)] = v;
  }
  __syncthreads();
  if (t == 0){
    #pragma unroll
    for (int h = 0; h < H; ++h)
      lsh[h] = 1.f / (red[h*4+0] + red[h*4+1] + red[h*4+2] + red[h*4+3]);
  }
  __syncthreads();
  // pass 3: aggregate
  float md[H], li[H], acc[H];
  #pragma unroll
  for (int h = 0; h < H; ++h){ md[h] = mfin[h]; li[h] = lsh[h]; acc[h] = 0.f; }
  for (int wdi = 0; wdi < 64; ++wdi){
    u64 bits = Mk[(size_t)d*64 + wdi];
    while (bits){
      int b = __builtin_ctzll(bits);
      bits &= bits - 1ull;
      int s = wdi*64 + b;
      #pragma unroll
      for (int h = 0; h < H; ++h){
        float e = erd[h] + el[s*H + h];
        e = e > 0.f ? e : 0.2f*e;
        float wt = __expf(e - md[h]) * li[h];
        acc[h] += wt * feat[(size_t)s*ldf + h*HD_ + t];
      }
    }
  }
  float v = 0.f;
  #pragma unroll
  for (int h = 0; h < H; ++h) v += acc[h];
  v += res[(size_t)d*ldres + t];
  v += bias[t];
  if (RELU) v = fmaxf(v, 0.f);
  out[(size_t)d*HD_ + t] = v;
}

// ---------- classifier head ----------
__global__ void head_k(const float* __restrict__ A, int K, const float* __restrict__ W,
                       const float* __restrict__ b, float* __restrict__ out){
  int row = blockIdx.x, t = threadIdx.x;
  float p[NC_];
  #pragma unroll
  for (int j = 0; j < NC_; ++j) p[j] = 0.f;
  for (int k = t; k < K; k += 256){
    float a = A[(size_t)row*K + k];
    #pragma unroll
    for (int j = 0; j < NC_; ++j) p[j] += a * W[k*NC_ + j];
  }
  #pragma unroll
  for (int j = 0; j < NC_; ++j){
    #pragma unroll
    for (int o = 32; o > 0; o >>= 1) p[j] += __shfl_down(p[j], o);
  }
  __shared__ float red[4][NC_];
  if ((t & 63) == 0){
    #pragma unroll
    for (int j = 0; j < NC_; ++j) red[t >> 6][j] = p[j];
  }
  __syncthreads();
  if (t < NC_)
    out[(size_t)row*NC_ + t] = red[0][t] + red[1][t] + red[2][t] + red[3][t] + b[t];
}

// ---------- launch ----------
extern "C" void kernel_launch(void* const* d_in, const int* in_sizes, int n_in,
                              void* d_out, int out_size, void* d_ws, size_t ws_size,
                              hipStream_t stream){
  const float* x   = (const float*)d_in[0];
  const float* W0  = (const float*)d_in[1];
  const float* al0 = (const float*)d_in[2];
  const float* ar0 = (const float*)d_in[3];
  const float* b0  = (const float*)d_in[4];
  const float* R0  = (const float*)d_in[5];
  const float* W1  = (const float*)d_in[6];
  const float* al1 = (const float*)d_in[7];
  const float* ar1 = (const float*)d_in[8];
  const float* b1  = (const float*)d_in[9];
  const float* R1  = (const float*)d_in[10];
  const float* W2  = (const float*)d_in[11];
  const float* al2 = (const float*)d_in[12];
  const float* ar2 = (const float*)d_in[13];
  const float* b2  = (const float*)d_in[14];
  const float* Wl1 = (const float*)d_in[15];
  const float* bl1 = (const float*)d_in[16];
  const float* Wc1 = (const float*)d_in[17];
  const float* bc1 = (const float*)d_in[18];
  const float* Wc2 = (const float*)d_in[19];
  const float* bc2 = (const float*)d_in[20];
  (void)in_sizes; (void)n_in; (void)out_size; (void)ws_size;

  char* ws = (char*)d_ws;
  size_t off = 0;
  auto alloc = [&](size_t bytes)->char*{
    char* p = ws + off; off += (bytes + 255) & ~(size_t)255; return p;
  };
  typedef unsigned short us;
  u64* MASK = (u64*)alloc((size_t)NNODE*64*8);
  us* W0h = (us*)alloc((size_t)1280*2048*2);  us* W0l = (us*)alloc((size_t)1280*2048*2);
  us* W1h = (us*)alloc((size_t)1280*256*2);   us* W1l = (us*)alloc((size_t)1280*256*2);
  us* W2h = (us*)alloc((size_t)256*256*2);    us* W2l = (us*)alloc((size_t)256*256*2);
  us* WLh = (us*)alloc((size_t)1024*2304*2);  us* WLl = (us*)alloc((size_t)1024*2304*2);
  float* BF0 = (float*)alloc(256*4);
  float* BF1 = (float*)alloc(256*4);
  float* EL  = (float*)alloc((size_t)NNODE*4*4);
  float* ER  = (float*)alloc((size_t)NNODE*4*4);
  us* XNh = (us*)alloc((size_t)NNODE*FIND*2);
  us* XNl = (us*)alloc((size_t)NNODE*FIND*2);
  us* Xh  = (us*)alloc((size_t)NNODE*FIND*2);
  us* Xl  = (us*)alloc((size_t)NNODE*FIND*2);
  float* FT = (float*)alloc((size_t)NNODE*1280*4);   // separate: mega reads XN while writing FT
  float* H1 = (float*)alloc((size_t)NNODE*HD_*4);
  float* H2 = (float*)alloc((size_t)NNODE*HD_*4);
  float* H3 = (float*)alloc((size_t)NNODE*HD_*4);
  us* H1h = (us*)alloc((size_t)NNODE*HD_*2);  us* H1l = (us*)alloc((size_t)NNODE*HD_*2);
  us* H2h = (us*)alloc((size_t)NNODE*HD_*2);  us* H2l = (us*)alloc((size_t)NNODE*HD_*2);
  us* H3h = (us*)alloc((size_t)NNODE*HD_*2);  us* H3l = (us*)alloc((size_t)NNODE*HD_*2);
  float* Z1 = (float*)alloc((size_t)NNODE*1024*4);

  float* out1 = (float*)d_out;
  float* out2 = out1 + (size_t)NNODE*NC_;

  // ---- weight & input prep ----
  foldT_k<1><<<512, 256, 0, stream>>>(W0, W0h, W0l, 2048, 1024, 32);
  foldT_k<4><<<128, 256, 0, stream>>>(R0, W0h + (size_t)1024*2048, W0l + (size_t)1024*2048, 2048, 256, 32);
  foldT_k<1><<< 64, 256, 0, stream>>>(W1, W1h, W1l, 256, 1024, 4);
  foldT_k<4><<< 16, 256, 0, stream>>>(R1, W1h + (size_t)1024*256, W1l + (size_t)1024*256, 256, 256, 4);
  foldT_k<1><<< 16, 256, 0, stream>>>(W2, W2h, W2l, 256, 256, 4);
  foldT_k<1><<<576, 256, 0, stream>>>(Wl1, WLh, WLl, 2304, 1024, 36);
  bfold_k<<<1, 256, 0, stream>>>(b0, BF0, 4, 256);
  bfold_k<<<1, 256, 0, stream>>>(b1, BF1, 4, 256);
  f2bf_k<<<(NNODE*FIND/4+255)/256, 256, 0, stream>>>(x, Xh, Xl, NNODE*FIND/4);
  rownorm_bf<<<NNODE, 256, 0, stream>>>(x, XNh, XNl);

  // ---- MEGA: Gram->mask (528) + GAT0 feat (320) + MLP x-part (256) ----
  mega_gemm<<<1104, 256, 0, stream>>>(XNh, XNl, Xh, Xl, W0h, W0l, WLh, WLl, FT, Z1, MASK);

  // ---- GAT layer 0 (post-GEMM) ----
  el_er_k<4><<<NNODE, 256, 0, stream>>>(FT, 1280, al0, ar0, EL, ER);
  sagg_k<4,true><<<NNODE, 256, 0, stream>>>(FT, 1280, MASK, EL, ER,
      FT + 1024, 1280, BF0, H1);

  // ---- GAT layer 1 ----
  f2bf_k<<<(NNODE*HD_/4+255)/256, 256, 0, stream>>>(H1, H1h, H1l, NNODE*HD_/4);
  gemm_bf<0><<<320, 256, 0, stream>>>(H1h, H1l, W1h, W1l, FT,
      256, 256, 256, 1280, 10, nullptr, 0.f);
  el_er_k<4><<<NNODE, 256, 0, stream>>>(FT, 1280, al1, ar1, EL, ER);
  sagg_k<4,true><<<NNODE, 256, 0, stream>>>(FT, 1280, MASK, EL, ER,
      FT + 1024, 1280, BF1, H2);

  // ---- GAT layer 2 (1 head, identity residual, no relu) ----
  f2bf_k<<<(NNODE*HD_/4+255)/256, 256, 0, stream>>>(H2, H2h, H2l, NNODE*HD_/4);
  gemm_bf<0><<<64, 256, 0, stream>>>(H2h, H2l, W2h, W2l, FT,
      256, 256, 256, 256, 2, nullptr, 0.f);
  el_er_k<1><<<NNODE, 256, 0, stream>>>(FT, 256, al2, ar2, EL, ER);
  sagg_k<1,false><<<NNODE, 256, 0, stream>>>(FT, 256, MASK, EL, ER,
      H2, 256, b2, H3);

  // ---- MLP: Z1 += h3-part, +bias, leaky ----
  f2bf_k<<<(NNODE*HD_/4+255)/256, 256, 0, stream>>>(H3, H3h, H3l, NNODE*HD_/4);
  gemm_bf<3><<<256, 256, 0, stream>>>(H3h, H3l, WLh + 2048, WLl + 2048, Z1,
      256, 256, 2304, 1024, 8, bl1, 0.01f);

  head_k<<<NNODE, 256, 0, stream>>>(Z1, 1024, Wc1, bc1, out1);
  head_k<<<NNODE, 256, 0, stream>>>(x, FIND, Wc2, bc2, out2);
}

// Round 6
// 681.196 us; speedup vs baseline: 2.9830x; 1.0719x over previous
//
#include <hip/hip_runtime.h>
#include <cstdint>
#include <cstddef>

#define NNODE 4096
#define FIND  2048
#define HD_   256
#define NC_   10
#define THRESH_ 0.05f

typedef unsigned long long u64;
typedef __attribute__((ext_vector_type(8))) short bf16x8;
typedef __attribute__((ext_vector_type(4))) float f32x4;

// ---------- bf16 split helpers ----------
__device__ inline unsigned short f2bf_rne(float f){
  unsigned u = __builtin_bit_cast(unsigned, f);
  unsigned r = u + 0x7FFFu + ((u >> 16) & 1u);
  return (unsigned short)(r >> 16);
}
__device__ inline float bf2f(unsigned short h){
  unsigned u = ((unsigned)h) << 16;
  return __builtin_bit_cast(float, u);
}

// async global->LDS, 16B per lane; lds dest is wave-uniform base (+lane*16 by HW)
__device__ __forceinline__ void gld16(const void* g, void* l){
  __builtin_amdgcn_global_load_lds(
      (const __attribute__((address_space(1))) unsigned int*)g,
      (__attribute__((address_space(3))) unsigned int*)l, 16, 0, 0);
}

// ---------- row normalize -> hi/lo bf16 ----------
__global__ void rownorm_bf(const float* __restrict__ x,
                           unsigned short* __restrict__ oh, unsigned short* __restrict__ ol){
  int row = blockIdx.x; int t = threadIdx.x;
  const float4* xr = reinterpret_cast<const float4*>(x + (size_t)row*FIND);
  float s = 0.f;
  #pragma unroll
  for (int i = 0; i < FIND/4/256; ++i){
    float4 v = xr[t + i*256];
    s += v.x*v.x + v.y*v.y + v.z*v.z + v.w*v.w;
  }
  #pragma unroll
  for (int o = 32; o > 0; o >>= 1) s += __shfl_down(s, o);
  __shared__ float red[4];
  __shared__ float invn;
  if ((t & 63) == 0) red[t >> 6] = s;
  __syncthreads();
  if (t == 0) invn = rsqrtf(red[0] + red[1] + red[2] + red[3]);
  __syncthreads();
  float inv = invn;
  #pragma unroll
  for (int i = 0; i < FIND/4/256; ++i){
    float4 v = xr[t + i*256];
    float a[4] = {v.x*inv, v.y*inv, v.z*inv, v.w*inv};
    ushort4 hv, lv;
    unsigned short* hp = &hv.x; unsigned short* lp = &lv.x;
    #pragma unroll
    for (int j = 0; j < 4; ++j){
      unsigned short h = f2bf_rne(a[j]);
      hp[j] = h; lp[j] = f2bf_rne(a[j] - bf2f(h));
    }
    size_t off = (size_t)row*FIND + (t + i*256)*4;
    *reinterpret_cast<ushort4*>(oh + off) = hv;
    *reinterpret_cast<ushort4*>(ol + off) = lv;
  }
}

// ---------- fp32 -> hi/lo bf16 (vectorized) ----------
__global__ void f2bf_k(const float* __restrict__ in, unsigned short* __restrict__ oh,
                       unsigned short* __restrict__ ol, int n4){
  int idx = blockIdx.x*256 + threadIdx.x;
  if (idx >= n4) return;
  float4 v = reinterpret_cast<const float4*>(in)[idx];
  float a[4] = {v.x, v.y, v.z, v.w};
  ushort4 hv, lv;
  unsigned short* hp = &hv.x; unsigned short* lp = &lv.x;
  #pragma unroll
  for (int j = 0; j < 4; ++j){
    unsigned short h = f2bf_rne(a[j]);
    hp[j] = h; lp[j] = f2bf_rne(a[j] - bf2f(h));
  }
  reinterpret_cast<ushort4*>(oh)[idx] = hv;
  reinterpret_cast<ushort4*>(ol)[idx] = lv;
}

// ---------- weight prep: R [K, H*F] -> outT [F, K] (sum over H), tiled LDS transpose ----------
template<int H>
__global__ void foldT_k(const float* __restrict__ R, unsigned short* __restrict__ oh,
                        unsigned short* __restrict__ ol, int K, int F, int ktiles){
  int bid = blockIdx.x;
  int f0 = (bid / ktiles) * 64, k0 = (bid % ktiles) * 64;
  __shared__ float tile[64][65];
  int t = threadIdx.x;
  {
    int tf = t & 63, tk4 = t >> 6;
    #pragma unroll
    for (int m = 0; m < 16; ++m){
      int kl = tk4 + m*4;
      float s = 0.f;
      #pragma unroll
      for (int h = 0; h < H; ++h)
        s += R[(size_t)(k0 + kl)*(H*F) + h*F + f0 + tf];
      tile[kl][tf] = s;
    }
  }
  __syncthreads();
  {
    int tk = t & 63, tf4 = t >> 6;
    #pragma unroll
    for (int m = 0; m < 16; ++m){
      int fl = tf4 + m*4;
      float s = tile[tk][fl];
      unsigned short hv = f2bf_rne(s);
      size_t o = (size_t)(f0 + fl)*K + k0 + tk;
      oh[o] = hv;
      ol[o] = f2bf_rne(s - bf2f(hv));
    }
  }
}

__global__ void bfold_k(const float* __restrict__ b, float* __restrict__ out, int H, int F){
  int f = threadIdx.x;
  if (f < F){
    float s = 0.f;
    for (int h = 0; h < H; ++h) s += b[h*F + f];
    out[f] = s;
  }
}

// ---------- MEGA GEMM: Gram(upper-tri, bitpack) + GAT0 feat + MLP x-part in one grid ----------
__global__ void mega_gemm(const unsigned short* __restrict__ XNh, const unsigned short* __restrict__ XNl,
                          const unsigned short* __restrict__ Xh,  const unsigned short* __restrict__ Xl,
                          const unsigned short* __restrict__ W0h, const unsigned short* __restrict__ W0l,
                          const unsigned short* __restrict__ WLh, const unsigned short* __restrict__ WLl,
                          float* __restrict__ FT, float* __restrict__ Z1, u64* __restrict__ Mk){
  __shared__ unsigned short smem[4*128*32];
  unsigned short* sAh = smem;
  unsigned short* sAl = smem + 4096;
  unsigned short* sBh = smem + 8192;
  unsigned short* sBl = smem + 12288;
  const int t = threadIdx.x, lane = t & 63, w = t >> 6;
  const int wr = w >> 1, wc = w & 1, l15 = lane & 15, lg = lane >> 4;

  int nwg = gridDim.x, bid = blockIdx.x;
  int wg = (bid & 7)*(nwg >> 3) + (bid >> 3);   // 1104 % 8 == 0 -> bijective

  int role, brow, bcol;
  const unsigned short *Ah, *Al, *Bh, *Bl;
  float* C = nullptr; int ldc = 0; size_t ldb;
  if (wg < 528){
    role = 0;
    int rem = wg, i = 0;
    while (rem >= 32 - i){ rem -= 32 - i; ++i; }
    brow = i; bcol = i + rem;
    Ah = XNh; Al = XNl; Bh = XNh; Bl = XNl; ldb = FIND;
  } else if (wg < 848){
    role = 1;
    int l = wg - 528; brow = l / 10; bcol = l % 10;
    Ah = Xh; Al = Xl; Bh = W0h; Bl = W0l; ldb = FIND;
    C = FT; ldc = 1280;
  } else {
    role = 2;
    int l = wg - 848; brow = l >> 3; bcol = l & 7;
    Ah = Xh; Al = Xl; Bh = WLh; Bl = WLl; ldb = 2304;
    C = Z1; ldc = 1024;
  }
  const int row0 = brow*128, col0 = bcol*128;

  const int c0 = 2*w, c1 = 2*w + 1;
  const int rsub = lane >> 2, piece = lane & 3;
  const size_t ld2a = (size_t)FIND*2, ld2b = ldb*2;
  const size_t a0 = (size_t)(row0 + 16*c0 + rsub)*ld2a + piece*16;
  const size_t a1 = (size_t)(row0 + 16*c1 + rsub)*ld2a + piece*16;
  const size_t b0 = (size_t)(col0 + 16*c0 + rsub)*ld2b + piece*16;
  const size_t b1 = (size_t)(col0 + 16*c1 + rsub)*ld2b + piece*16;
  const char* pA0h = (const char*)Ah + a0;  const char* pA1h = (const char*)Ah + a1;
  const char* pA0l = (const char*)Al + a0;  const char* pA1l = (const char*)Al + a1;
  const char* pB0h = (const char*)Bh + b0;  const char* pB1h = (const char*)Bh + b1;
  const char* pB0l = (const char*)Bl + b0;  const char* pB1l = (const char*)Bl + b1;
  char* lA0h = (char*)sAh + c0*1024;  char* lA1h = (char*)sAh + c1*1024;
  char* lA0l = (char*)sAl + c0*1024;  char* lA1l = (char*)sAl + c1*1024;
  char* lB0h = (char*)sBh + c0*1024;  char* lB1h = (char*)sBh + c1*1024;
  char* lB0l = (char*)sBl + c0*1024;  char* lB1l = (char*)sBl + c1*1024;

  f32x4 acc[4][4] = {};
  for (int kt = 0; kt < 64; ++kt){
    __syncthreads();
    gld16(pA0h, lA0h); gld16(pA1h, lA1h);
    gld16(pA0l, lA0l); gld16(pA1l, lA1l);
    gld16(pB0h, lB0h); gld16(pB1h, lB1h);
    gld16(pB0l, lB0l); gld16(pB1l, lB1l);
    pA0h += 64; pA1h += 64; pA0l += 64; pA1l += 64;
    pB0h += 64; pB1h += 64; pB0l += 64; pB1l += 64;
    __syncthreads();
    bf16x8 fb_h[4], fb_l[4];
    #pragma unroll
    for (int j = 0; j < 4; ++j){
      int bo = (wc*64 + j*16 + l15)*32 + lg*8;
      fb_h[j] = *reinterpret_cast<const bf16x8*>(sBh + bo);
      fb_l[j] = *reinterpret_cast<const bf16x8*>(sBl + bo);
    }
    #pragma unroll
    for (int i = 0; i < 4; ++i){
      int ao = (wr*64 + i*16 + l15)*32 + lg*8;
      bf16x8 fah = *reinterpret_cast<const bf16x8*>(sAh + ao);
      bf16x8 fal = *reinterpret_cast<const bf16x8*>(sAl + ao);
      #pragma unroll
      for (int j = 0; j < 4; ++j){
        acc[i][j] = __builtin_amdgcn_mfma_f32_16x16x32_bf16(fah, fb_h[j], acc[i][j], 0, 0, 0);
        acc[i][j] = __builtin_amdgcn_mfma_f32_16x16x32_bf16(fah, fb_l[j], acc[i][j], 0, 0, 0);
        acc[i][j] = __builtin_amdgcn_mfma_f32_16x16x32_bf16(fal, fb_h[j], acc[i][j], 0, 0, 0);
      }
    }
  }

  if (role == 0){
    #pragma unroll
    for (int i = 0; i < 4; ++i){
      #pragma unroll
      for (int r = 0; r < 4; ++r){
        u64 bits = 0ull;
        #pragma unroll
        for (int j = 0; j < 4; ++j)
          if (acc[i][j][r] > THRESH_) bits |= 1ull << (j*16 + l15);
        #pragma unroll
        for (int m = 1; m <= 8; m <<= 1) bits |= __shfl_xor(bits, m);
        if (l15 == 0){
          int gr = row0 + wr*64 + i*16 + lg*4 + r;
          Mk[(size_t)gr*64 + (col0 >> 6) + wc] = bits;
        }
      }
    }
    if (row0 != col0){
      #pragma unroll
      for (int j = 0; j < 4; ++j){
        u64 tb = 0ull;
        #pragma unroll
        for (int i = 0; i < 4; ++i)
          #pragma unroll
          for (int r = 0; r < 4; ++r)
            if (acc[i][j][r] > THRESH_) tb |= 1ull << (i*16 + lg*4 + r);
        tb |= __shfl_xor(tb, 16);
        tb |= __shfl_xor(tb, 32);
        if (lg == 0){
          int gc = col0 + wc*64 + j*16 + l15;
          Mk[(size_t)gc*64 + (row0 >> 6) + wr] = tb;
        }
      }
    }
  } else {
    #pragma unroll
    for (int i = 0; i < 4; ++i){
      int gr = row0 + wr*64 + i*16 + lg*4;
      #pragma unroll
      for (int j = 0; j < 4; ++j){
        int gc = col0 + wc*64 + j*16 + l15;
        #pragma unroll
        for (int r = 0; r < 4; ++r)
          C[(size_t)(gr + r)*ldc + gc] = acc[i][j][r];
      }
    }
  }
}

// ---------- split-bf16 MFMA NT GEMM (m97 structure) for short-K layers ----------
// EPI: 0 = store C; 3 = C += acc, +bias, leaky(param)
template<int EPI>
__global__ void gemm_bf(const unsigned short* __restrict__ Ah, const unsigned short* __restrict__ Al,
                        const unsigned short* __restrict__ Bh, const unsigned short* __restrict__ Bl,
                        float* __restrict__ C,
                        int K, int lda, int ldb, int ldc, int gridx,
                        const float* __restrict__ bias, float param){
  __shared__ unsigned short smem[4*128*32];
  unsigned short* sAh = smem;
  unsigned short* sAl = smem + 4096;
  unsigned short* sBh = smem + 8192;
  unsigned short* sBl = smem + 12288;
  const int t = threadIdx.x, lane = t & 63, w = t >> 6;
  const int wr = w >> 1, wc = w & 1, l15 = lane & 15, lg = lane >> 4;

  int nwg = gridDim.x, bid = blockIdx.x;
  int wg = ((nwg & 7) == 0) ? ((bid & 7)*(nwg >> 3) + (bid >> 3)) : bid;
  int brow = wg / gridx, bcol = wg % gridx;
  const int row0 = brow*128, col0 = bcol*128;

  const int c0 = 2*w, c1 = 2*w + 1;
  const int rsub = lane >> 2, piece = lane & 3;
  const size_t ld2a = (size_t)lda*2, ld2b = (size_t)ldb*2;
  const size_t a0 = (size_t)(row0 + 16*c0 + rsub)*ld2a + piece*16;
  const size_t a1 = (size_t)(row0 + 16*c1 + rsub)*ld2a + piece*16;
  const size_t b0 = (size_t)(col0 + 16*c0 + rsub)*ld2b + piece*16;
  const size_t b1 = (size_t)(col0 + 16*c1 + rsub)*ld2b + piece*16;
  const char* pA0h = (const char*)Ah + a0;  const char* pA1h = (const char*)Ah + a1;
  const char* pA0l = (const char*)Al + a0;  const char* pA1l = (const char*)Al + a1;
  const char* pB0h = (const char*)Bh + b0;  const char* pB1h = (const char*)Bh + b1;
  const char* pB0l = (const char*)Bl + b0;  const char* pB1l = (const char*)Bl + b1;
  char* lA0h = (char*)sAh + c0*1024;  char* lA1h = (char*)sAh + c1*1024;
  char* lA0l = (char*)sAl + c0*1024;  char* lA1l = (char*)sAl + c1*1024;
  char* lB0h = (char*)sBh + c0*1024;  char* lB1h = (char*)sBh + c1*1024;
  char* lB0l = (char*)sBl + c0*1024;  char* lB1l = (char*)sBl + c1*1024;

  f32x4 acc[4][4] = {};
  const int nk = K >> 5;
  for (int kt = 0; kt < nk; ++kt){
    __syncthreads();
    gld16(pA0h, lA0h); gld16(pA1h, lA1h);
    gld16(pA0l, lA0l); gld16(pA1l, lA1l);
    gld16(pB0h, lB0h); gld16(pB1h, lB1h);
    gld16(pB0l, lB0l); gld16(pB1l, lB1l);
    pA0h += 64; pA1h += 64; pA0l += 64; pA1l += 64;
    pB0h += 64; pB1h += 64; pB0l += 64; pB1l += 64;
    __syncthreads();
    bf16x8 fb_h[4], fb_l[4];
    #pragma unroll
    for (int j = 0; j < 4; ++j){
      int bo = (wc*64 + j*16 + l15)*32 + lg*8;
      fb_h[j] = *reinterpret_cast<const bf16x8*>(sBh + bo);
      fb_l[j] = *reinterpret_cast<const bf16x8*>(sBl + bo);
    }
    #pragma unroll
    for (int i = 0; i < 4; ++i){
      int ao = (wr*64 + i*16 + l15)*32 + lg*8;
      bf16x8 fah = *reinterpret_cast<const bf16x8*>(sAh + ao);
      bf16x8 fal = *reinterpret_cast<const bf16x8*>(sAl + ao);
      #pragma unroll
      for (int j = 0; j < 4; ++j){
        acc[i][j] = __builtin_amdgcn_mfma_f32_16x16x32_bf16(fah, fb_h[j], acc[i][j], 0, 0, 0);
        acc[i][j] = __builtin_amdgcn_mfma_f32_16x16x32_bf16(fah, fb_l[j], acc[i][j], 0, 0, 0);
        acc[i][j] = __builtin_amdgcn_mfma_f32_16x16x32_bf16(fal, fb_h[j], acc[i][j], 0, 0, 0);
      }
    }
  }

  #pragma unroll
  for (int i = 0; i < 4; ++i){
    int gr = row0 + wr*64 + i*16 + lg*4;
    #pragma unroll
    for (int j = 0; j < 4; ++j){
      int gc = col0 + wc*64 + j*16 + l15;
      #pragma unroll
      for (int r = 0; r < 4; ++r){
        float v = acc[i][j][r];
        size_t o = (size_t)(gr + r)*ldc + gc;
        if (EPI == 3){
          v += C[o] + bias[gc];
          v = v > 0.f ? v : param*v;
        }
        C[o] = v;
      }
    }
  }
}

// ---------- el / er per node ----------
template<int H>
__global__ void el_er_k(const float* __restrict__ feat, int ldf,
                        const float* __restrict__ al, const float* __restrict__ ar,
                        float* __restrict__ el, float* __restrict__ er){
  int n = blockIdx.x, t = threadIdx.x;
  __shared__ float red[8];
  #pragma unroll
  for (int h = 0; h < H; ++h){
    float v = feat[(size_t)n*ldf + h*HD_ + t];
    float a = v * al[h*HD_ + t];
    float b = v * ar[h*HD_ + t];
    #pragma unroll
    for (int o = 32; o > 0; o >>= 1){ a += __shfl_down(a, o); b += __shfl_down(b, o); }
    if ((t & 63) == 0){ red[t >> 6] = a; red[4 + (t >> 6)] = b; }
    __syncthreads();
    if (t == 0){
      el[n*H + h] = red[0] + red[1] + red[2] + red[3];
      er[n*H + h] = red[4] + red[5] + red[6] + red[7];
    }
    __syncthreads();
  }
}

// ---------- fused softmax stats + aggregation per dst ----------
// Pass 3 layout: H=4 -> thread t owns head h=t>>6, float4 feature slice 4*(t&63);
//                H=1 -> lane-group g=t>>6 walks mask words [16g,16g+16), slice 4*(t&63).
// LDS reduce over the 4 groups (heads or src-partitions). Emits hi/lo bf16 (+opt fp32).
template<int H, bool RELU, bool OUTF32>
__global__ void sagg_k(const float* __restrict__ feat, int ldf,
                       const u64* __restrict__ Mk,
                       const float* __restrict__ el, const float* __restrict__ er,
                       const float* __restrict__ res, int ldres,
                       const float* __restrict__ bias,
                       float* __restrict__ outf,
                       unsigned short* __restrict__ oh, unsigned short* __restrict__ ol){
  int d = blockIdx.x, t = threadIdx.x;
  float erd[H];
  #pragma unroll
  for (int h = 0; h < H; ++h) erd[h] = er[d*H + h];
  __shared__ float red[H*4];
  __shared__ float mfin[H];
  __shared__ float lsh[H];
  // pass 1: max
  float mx[H];
  #pragma unroll
  for (int h = 0; h < H; ++h) mx[h] = -1e30f;
  for (int s = t; s < NNODE; s += 256){
    u64 wd = Mk[(size_t)d*64 + (s >> 6)];
    if ((wd >> (s & 63)) & 1ull){
      #pragma unroll
      for (int h = 0; h < H; ++h){
        float e = erd[h] + el[s*H + h];
        e = e > 0.f ? e : 0.2f*e;
        mx[h] = fmaxf(mx[h], e);
      }
    }
  }
  #pragma unroll
  for (int h = 0; h < H; ++h){
    float v = mx[h];
    #pragma unroll
    for (int o = 32; o > 0; o >>= 1) v = fmaxf(v, __shfl_down(v, o));
    if ((t & 63) == 0) red[h*4 + (t >> 6)] = v;
  }
  __syncthreads();
  if (t == 0){
    #pragma unroll
    for (int h = 0; h < H; ++h)
      mfin[h] = fmaxf(fmaxf(red[h*4+0], red[h*4+1]), fmaxf(red[h*4+2], red[h*4+3]));
  }
  __syncthreads();
  // pass 2: denom
  float sm[H];
  #pragma unroll
  for (int h = 0; h < H; ++h) sm[h] = 0.f;
  for (int s = t; s < NNODE; s += 256){
    u64 wd = Mk[(size_t)d*64 + (s >> 6)];
    if ((wd >> (s & 63)) & 1ull){
      #pragma unroll
      for (int h = 0; h < H; ++h){
        float e = erd[h] + el[s*H + h];
        e = e > 0.f ? e : 0.2f*e;
        sm[h] += __expf(e - mfin[h]);
      }
    }
  }
  __syncthreads();
  #pragma unroll
  for (int h = 0; h < H; ++h){
    float v = sm[h];
    #pragma unroll
    for (int o = 32; o > 0; o >>= 1) v += __shfl_down(v, o);
    if ((t & 63) == 0) red[h*4 + (t >> 6)] = v;
  }
  __syncthreads();
  if (t == 0){
    #pragma unroll
    for (int h = 0; h < H; ++h)
      lsh[h] = 1.f / (red[h*4+0] + red[h*4+1] + red[h*4+2] + red[h*4+3]);
  }
  __syncthreads();
  // pass 3: float4 gather, 1 exp per edge per thread
  const int g = t >> 6, q = t & 63;
  const int h = (H == 4) ? g : 0;
  const int wlo = (H == 1) ? g*16 : 0;
  const int whi = (H == 1) ? wlo + 16 : 64;
  const float erdh = erd[h], mdh = mfin[h], lih = lsh[h];
  const float* fbase = feat + 4*q + ((H == 4) ? 256*g : 0);
  float4 acc = {0.f, 0.f, 0.f, 0.f};
  for (int wdi = wlo; wdi < whi; ++wdi){
    u64 bits = Mk[(size_t)d*64 + wdi];
    while (bits){
      int b = __builtin_ctzll(bits);
      bits &= bits - 1ull;
      int s = wdi*64 + b;
      float e = erdh + el[s*H + h];
      e = e > 0.f ? e : 0.2f*e;
      float wt = __expf(e - mdh) * lih;
      float4 v = *reinterpret_cast<const float4*>(fbase + (size_t)s*ldf);
      acc.x += wt*v.x; acc.y += wt*v.y; acc.z += wt*v.z; acc.w += wt*v.w;
    }
  }
  __shared__ float lred[4][256];
  lred[g][q*4+0] = acc.x; lred[g][q*4+1] = acc.y;
  lred[g][q*4+2] = acc.z; lred[g][q*4+3] = acc.w;
  __syncthreads();
  float v = ((lred[0][t] + lred[1][t]) + lred[2][t]) + lred[3][t];
  v += res[(size_t)d*ldres + t];
  v += bias[t];
  if (RELU) v = fmaxf(v, 0.f);
  if (OUTF32) outf[(size_t)d*HD_ + t] = v;
  unsigned short hv = f2bf_rne(v);
  oh[(size_t)d*HD_ + t] = hv;
  ol[(size_t)d*HD_ + t] = f2bf_rne(v - bf2f(hv));
}

// ---------- classifier head ----------
__global__ void head_k(const float* __restrict__ A, int K, const float* __restrict__ W,
                       const float* __restrict__ b, float* __restrict__ out){
  int row = blockIdx.x, t = threadIdx.x;
  float p[NC_];
  #pragma unroll
  for (int j = 0; j < NC_; ++j) p[j] = 0.f;
  for (int k = t; k < K; k += 256){
    float a = A[(size_t)row*K + k];
    #pragma unroll
    for (int j = 0; j < NC_; ++j) p[j] += a * W[k*NC_ + j];
  }
  #pragma unroll
  for (int j = 0; j < NC_; ++j){
    #pragma unroll
    for (int o = 32; o > 0; o >>= 1) p[j] += __shfl_down(p[j], o);
  }
  __shared__ float red[4][NC_];
  if ((t & 63) == 0){
    #pragma unroll
    for (int j = 0; j < NC_; ++j) red[t >> 6][j] = p[j];
  }
  __syncthreads();
  if (t < NC_)
    out[(size_t)row*NC_ + t] = red[0][t] + red[1][t] + red[2][t] + red[3][t] + b[t];
}

// ---------- launch ----------
extern "C" void kernel_launch(void* const* d_in, const int* in_sizes, int n_in,
                              void* d_out, int out_size, void* d_ws, size_t ws_size,
                              hipStream_t stream){
  const float* x   = (const float*)d_in[0];
  const float* W0  = (const float*)d_in[1];
  const float* al0 = (const float*)d_in[2];
  const float* ar0 = (const float*)d_in[3];
  const float* b0  = (const float*)d_in[4];
  const float* R0  = (const float*)d_in[5];
  const float* W1  = (const float*)d_in[6];
  const float* al1 = (const float*)d_in[7];
  const float* ar1 = (const float*)d_in[8];
  const float* b1  = (const float*)d_in[9];
  const float* R1  = (const float*)d_in[10];
  const float* W2  = (const float*)d_in[11];
  const float* al2 = (const float*)d_in[12];
  const float* ar2 = (const float*)d_in[13];
  const float* b2  = (const float*)d_in[14];
  const float* Wl1 = (const float*)d_in[15];
  const float* bl1 = (const float*)d_in[16];
  const float* Wc1 = (const float*)d_in[17];
  const float* bc1 = (const float*)d_in[18];
  const float* Wc2 = (const float*)d_in[19];
  const float* bc2 = (const float*)d_in[20];
  (void)in_sizes; (void)n_in; (void)out_size; (void)ws_size;

  char* ws = (char*)d_ws;
  size_t off = 0;
  auto alloc = [&](size_t bytes)->char*{
    char* p = ws + off; off += (bytes + 255) & ~(size_t)255; return p;
  };
  typedef unsigned short us;
  u64* MASK = (u64*)alloc((size_t)NNODE*64*8);
  us* W0h = (us*)alloc((size_t)1280*2048*2);  us* W0l = (us*)alloc((size_t)1280*2048*2);
  us* W1h = (us*)alloc((size_t)1280*256*2);   us* W1l = (us*)alloc((size_t)1280*256*2);
  us* W2h = (us*)alloc((size_t)256*256*2);    us* W2l = (us*)alloc((size_t)256*256*2);
  us* WLh = (us*)alloc((size_t)1024*2304*2);  us* WLl = (us*)alloc((size_t)1024*2304*2);
  float* BF0 = (float*)alloc(256*4);
  float* BF1 = (float*)alloc(256*4);
  float* EL  = (float*)alloc((size_t)NNODE*4*4);
  float* ER  = (float*)alloc((size_t)NNODE*4*4);
  us* XNh = (us*)alloc((size_t)NNODE*FIND*2);
  us* XNl = (us*)alloc((size_t)NNODE*FIND*2);
  us* Xh  = (us*)alloc((size_t)NNODE*FIND*2);
  us* Xl  = (us*)alloc((size_t)NNODE*FIND*2);
  float* FT = (float*)alloc((size_t)NNODE*1280*4);   // mega reads XN while writing FT
  float* H2 = (float*)alloc((size_t)NNODE*HD_*4);    // fp32 needed as layer-2 identity residual
  us* H1h = (us*)alloc((size_t)NNODE*HD_*2);  us* H1l = (us*)alloc((size_t)NNODE*HD_*2);
  us* H2h = (us*)alloc((size_t)NNODE*HD_*2);  us* H2l = (us*)alloc((size_t)NNODE*HD_*2);
  us* H3h = (us*)alloc((size_t)NNODE*HD_*2);  us* H3l = (us*)alloc((size_t)NNODE*HD_*2);
  float* Z1 = (float*)alloc((size_t)NNODE*1024*4);

  float* out1 = (float*)d_out;
  float* out2 = out1 + (size_t)NNODE*NC_;

  // ---- weight & input prep ----
  foldT_k<1><<<512, 256, 0, stream>>>(W0, W0h, W0l, 2048, 1024, 32);
  foldT_k<4><<<128, 256, 0, stream>>>(R0, W0h + (size_t)1024*2048, W0l + (size_t)1024*2048, 2048, 256, 32);
  foldT_k<1><<< 64, 256, 0, stream>>>(W1, W1h, W1l, 256, 1024, 4);
  foldT_k<4><<< 16, 256, 0, stream>>>(R1, W1h + (size_t)1024*256, W1l + (size_t)1024*256, 256, 256, 4);
  foldT_k<1><<< 16, 256, 0, stream>>>(W2, W2h, W2l, 256, 256, 4);
  foldT_k<1><<<576, 256, 0, stream>>>(Wl1, WLh, WLl, 2304, 1024, 36);
  bfold_k<<<1, 256, 0, stream>>>(b0, BF0, 4, 256);
  bfold_k<<<1, 256, 0, stream>>>(b1, BF1, 4, 256);
  f2bf_k<<<(NNODE*FIND/4+255)/256, 256, 0, stream>>>(x, Xh, Xl, NNODE*FIND/4);
  rownorm_bf<<<NNODE, 256, 0, stream>>>(x, XNh, XNl);

  // ---- MEGA: Gram->mask (528) + GAT0 feat (320) + MLP x-part (256) ----
  mega_gemm<<<1104, 256, 0, stream>>>(XNh, XNl, Xh, Xl, W0h, W0l, WLh, WLl, FT, Z1, MASK);

  // ---- GAT layer 0 ----
  el_er_k<4><<<NNODE, 256, 0, stream>>>(FT, 1280, al0, ar0, EL, ER);
  sagg_k<4,true,false><<<NNODE, 256, 0, stream>>>(FT, 1280, MASK, EL, ER,
      FT + 1024, 1280, BF0, nullptr, H1h, H1l);

  // ---- GAT layer 1 ----
  gemm_bf<0><<<320, 256, 0, stream>>>(H1h, H1l, W1h, W1l, FT,
      256, 256, 256, 1280, 10, nullptr, 0.f);
  el_er_k<4><<<NNODE, 256, 0, stream>>>(FT, 1280, al1, ar1, EL, ER);
  sagg_k<4,true,true><<<NNODE, 256, 0, stream>>>(FT, 1280, MASK, EL, ER,
      FT + 1024, 1280, BF1, H2, H2h, H2l);

  // ---- GAT layer 2 (1 head, identity residual, no relu) ----
  gemm_bf<0><<<64, 256, 0, stream>>>(H2h, H2l, W2h, W2l, FT,
      256, 256, 256, 256, 2, nullptr, 0.f);
  el_er_k<1><<<NNODE, 256, 0, stream>>>(FT, 256, al2, ar2, EL, ER);
  sagg_k<1,false,false><<<NNODE, 256, 0, stream>>>(FT, 256, MASK, EL, ER,
      H2, 256, b2, nullptr, H3h, H3l);

  // ---- MLP: Z1 += h3-part, +bias, leaky ----
  gemm_bf<3><<<256, 256, 0, stream>>>(H3h, H3l, WLh + 2048, WLl + 2048, Z1,
      256, 256, 2304, 1024, 8, bl1, 0.01f);

  head_k<<<NNODE, 256, 0, stream>>>(Z1, 1024, Wc1, bc1, out1);
  head_k<<<NNODE, 256, 0, stream>>>(x, FIND, Wc2, bc2, out2);
}